// Round 7
// baseline (1767.112 us; speedup 1.0000x reference)
//
#include <hip/hip_runtime.h>
#include <math.h>

#define B_ 4
#define NM 4
#define T_ 1024
#define D_ 256
#define DK_ 16
#define DV_ 64
#define DKP_ 32
#define H_ 8
#define E_ 4
#define HE_ 32
#define R_ 4
#define DA_ 25
#define DPG_ 316
#define ND_ 1024
#define DATTN_ 512
#define BT_ 4096
#define TBH 16
#define TB 32
#define TT 64

// ---- workspace layout (float offsets) ----
#define OFF_CNT     0                          // 64 ints: cnt_kv[32], cnt_q[32]
#define OFF_ACCPRE  256                        // BT*512
#define OFF_ACCPOST (OFF_ACCPRE + BT_*512)     // BT*256
#define OFF_ACCRES  (OFF_ACCPOST + BT_*256)    // BT*16
#define OFF_ACCHP   (OFF_ACCRES + BT_*16)      // BT*4
#define OFF_QH      (OFF_ACCHP + BT_*4)        // H*BT*32 (zeroed: unselected q stays 0)
#define ZERO_END    (OFF_QH + H_*BT_*32)
#define OFF_KH      ZERO_END                   // H*BT*32
#define OFF_VH      (OFF_KH + H_*BT_*32)       // H*BT*64
#define OFF_ALH     (OFF_VH + H_*BT_*64)      // H*BT*32
#define OFF_BEH     (OFF_ALH + H_*BT_*32)      // H*BT
#define OFF_LKV     (OFF_BEH + H_*BT_)         // 32*BT ints
#define OFF_LQ      (OFF_LKV + HE_*BT_)        // 32*BT ints
#define OFF_RMS     (OFF_LQ + HE_*BT_)         // BT
#define OFF_ATTN    (OFF_RMS + BT_)            // BT*512
#define OFF_TRIG    (OFF_ATTN + BT_*512)       // 4*T*DK
#define OFF_HEKV    (OFF_TRIG + 4*T_*DK_)      // H*BT*256
#define OFF_HEQ     (OFF_HEKV + H_*BT_*256)    // H*BT*256
#define WS_FLOATS   (OFF_HEQ + H_*BT_*256)

__device__ __forceinline__ float sigf(float x){ return 1.0f/(1.0f+expf(-x)); }
__device__ __forceinline__ float siluf(float x){ return x/(1.0f+expf(-x)); }
__device__ __forceinline__ float softplusf(float x){ return fmaxf(x,0.0f)+log1pf(expf(-fabsf(x))); }

// ---------------- K0: trig tables ----------------
__global__ __launch_bounds__(256) void k_trig(const float* __restrict__ delta, float* __restrict__ ws){
  int idx = blockIdx.x*256 + threadIdx.x;
  int t = idx >> 4, k = idx & 15;
  double fr = pow(10000.0, (double)k / 16.0);
  float freq = (float)fr;
  float pq = (float)t * freq;
  float sg = sigf(delta[k]);
  float shift = (float)(2.0*M_PI) * sg;
  float pk = pq - shift;
  float* tr = ws + OFF_TRIG;
  tr[idx]         = (float)cos((double)pq);
  tr[16384+idx]   = (float)sin((double)pq);
  tr[32768+idx]   = (float)cos((double)pk);
  tr[49152+idx]   = (float)sin((double)pk);
}

// ---------------- K1: RMS scale + routing + gather lists ----------------
__global__ __launch_bounds__(256) void k_route(const float* __restrict__ stream,
    const float* __restrict__ q_router, const float* __restrict__ kv_router,
    float* __restrict__ ws){
  __shared__ float s_route[256];
  __shared__ float s_red[4];
  __shared__ float s_log[64];
  int tok = blockIdx.x; int b = tok >> 10, t = tok & 1023;
  int d = threadIdx.x;
  const float* sp = stream + ((size_t)(b*4)*1024 + t)*256 + d;
  float s0 = sp[0];
  float s1 = sp[1024*256];
  float s2 = sp[2*1024*256];
  float s3 = sp[3*1024*256];
  s_route[d] = (((s0+s1)+s2)+s3)*0.25f;
  float ssp = s0*s0+s1*s1+s2*s2+s3*s3;
  for (int off=32; off; off>>=1) ssp += __shfl_xor(ssp, off, 64);
  if ((d & 63)==0) s_red[d>>6] = ssp;
  __syncthreads();
  if (d==0){
    float ss = ((s_red[0]+s_red[1])+s_red[2])+s_red[3];
    float mean = ss*(1.0f/1024.0f) + 1e-6f;
    ws[OFF_RMS + tok] = (float)(1.0/sqrt((double)mean));
  }
  if (d < 64){
    int lane = d;
    int r = lane>>5, h = (lane>>2)&7, e = lane&3;
    const float* R = (r ? kv_router : q_router) + h*1024 + e;
    float acc = 0.f;
    for (int dd=0; dd<256; ++dd) acc = fmaf(s_route[dd], R[dd*4], acc);
    s_log[lane] = fminf(fmaxf(acc,-10.f),10.f);
  }
  if (d < 16){
    int r = d>>3, h = d&7;
    int base = r*32 + h*4;
    int best=0; float bv = s_log[base];
    for (int e=1;e<4;e++){ float v=s_log[base+e]; if (v>bv){bv=v;best=e;} }
    int* cnt = (int*)ws;
    if (r==1){
      int* lst = (int*)(ws + OFF_LKV);
      int pos = atomicAdd(&cnt[h*4+best],1);
      lst[(h*4+best)*BT_ + pos] = tok;
    } else if (best>0){
      int* lst = (int*)(ws + OFF_LQ);
      int pos = atomicAdd(&cnt[32 + h*4+best],1);
      lst[(h*4+best)*BT_ + pos] = tok;
    }
  }
}

// ---------------- K2a: he for kv-selected tokens (R4 phase A, writes global) ----------------
__global__ __launch_bounds__(256) void k_he_kv(
    const float* __restrict__ stream, float* ws,
    const float* __restrict__ mhc_norm_w, const float* __restrict__ phi_pre,
    const float* __restrict__ phi_post, const float* __restrict__ phi_res,
    const float* __restrict__ b_pre, const float* __restrict__ b_post, const float* __restrict__ b_res,
    const float* __restrict__ a_pre, const float* __restrict__ a_post, const float* __restrict__ a_res,
    const float* __restrict__ norm_w)
{
  int g = blockIdx.y; int h = g>>2;
  const int* cnt = (const int*)ws;
  int c = cnt[g];
  int start = blockIdx.x*TBH;
  if (start >= c) return;
  int nact = min(TBH, c-start);

  __shared__ float s_phi[24][128];
  __shared__ float s_dots[TBH][24];
  __shared__ float s_nw[1024];
  __shared__ float s_gnw[256];
  __shared__ int s_tok[TBH];
  int tid = threadIdx.x;
  if (tid < TBH) s_tok[tid] = (tid < nact) ? ((const int*)(ws + OFF_LKV))[g*BT_ + start + tid] : -1;
  for (int i=tid;i<1024;i+=256) s_nw[i] = mhc_norm_w[g*1024+i];
  s_gnw[tid] = norm_w[g*256+tid];
  __syncthreads();

  float aP = a_pre[g], aQ = a_post[g], aR = a_res[g];
  int hw = tid>>5, lane = tid&31;
  int ti0 = hw, ti1 = hw+8;
  int tok0 = s_tok[ti0], tok1 = s_tok[ti1];
  const float* sb0 = stream + (tok0>=0 ? ((size_t)(tok0>>10)*4*262144 + (size_t)(tok0&1023)*256) : 0);
  const float* sb1 = stream + (tok1>=0 ? ((size_t)(tok1>>10)*4*262144 + (size_t)(tok1&1023)*256) : 0);
  float rn0 = (tok0>=0) ? ws[OFF_RMS + tok0] : 0.f;
  float rn1 = (tok1>=0) ? ws[OFF_RMS + tok1] : 0.f;

  float dA0[24], dA1[24];
  #pragma unroll
  for (int n=0;n<24;++n){ dA0[n]=0.f; dA1[n]=0.f; }
  for (int cc=0; cc<8; ++cc){
    __syncthreads();
    {
      int kk = tid & 127;
      int np = tid >> 7;
      int kg = cc*128 + kk;
      #pragma unroll
      for (int it=0; it<12; ++it){
        int n = np + it*2;
        float v;
        if (n < 4)       v = phi_pre [(size_t)g*4096  + (size_t)kg*4  + n];
        else if (n < 8)  v = phi_post[(size_t)g*4096  + (size_t)kg*4  + (n-4)];
        else             v = phi_res [(size_t)g*16384 + (size_t)kg*16 + (n-8)];
        s_phi[n][kk] = v;
      }
    }
    __syncthreads();
    int rr = cc>>1;
    int off = (cc&1)*128 + lane*4;
    float4 x0 = *(const float4*)(sb0 + (size_t)rr*262144 + off);
    float4 x1 = *(const float4*)(sb1 + (size_t)rr*262144 + off);
    float4 nw4 = *(const float4*)(&s_nw[cc*128 + lane*4]);
    x0.x *= rn0*nw4.x; x0.y *= rn0*nw4.y; x0.z *= rn0*nw4.z; x0.w *= rn0*nw4.w;
    x1.x *= rn1*nw4.x; x1.y *= rn1*nw4.y; x1.z *= rn1*nw4.z; x1.w *= rn1*nw4.w;
    #pragma unroll
    for (int n=0;n<24;++n){
      float4 p4 = *(const float4*)(&s_phi[n][lane*4]);
      dA0[n] = fmaf(x0.w,p4.w,fmaf(x0.z,p4.z,fmaf(x0.y,p4.y,fmaf(x0.x,p4.x,dA0[n]))));
      dA1[n] = fmaf(x1.w,p4.w,fmaf(x1.z,p4.z,fmaf(x1.y,p4.y,fmaf(x1.x,p4.x,dA1[n]))));
    }
  }
  #pragma unroll
  for (int n=0;n<24;++n){
    float v0=dA0[n], v1=dA1[n];
    v0 += __shfl_xor(v0,16,32); v0 += __shfl_xor(v0,8,32); v0 += __shfl_xor(v0,4,32); v0 += __shfl_xor(v0,2,32); v0 += __shfl_xor(v0,1,32);
    v1 += __shfl_xor(v1,16,32); v1 += __shfl_xor(v1,8,32); v1 += __shfl_xor(v1,4,32); v1 += __shfl_xor(v1,2,32); v1 += __shfl_xor(v1,1,32);
    dA0[n]=v0; dA1[n]=v1;
  }
  float bp0=b_pre[g*4+0], bp1=b_pre[g*4+1], bp2=b_pre[g*4+2], bp3=b_pre[g*4+3];

  auto finish = [&](int ti, int tok, const float (&dAx)[24], const float* sbx){
    if (tok < 0) return;
    if (lane==0){
      #pragma unroll
      for (int n=0;n<24;++n) s_dots[ti][n] = dAx[n];
    }
    float g0 = sigf(aP*dAx[0]+bp0);
    float g1 = sigf(aP*dAx[1]+bp1);
    float g2 = sigf(aP*dAx[2]+bp2);
    float g3 = sigf(aP*dAx[3]+bp3);
    if (lane>=16 && lane<20){
      int n = lane-16;
      float hp = 2.f*sigf(aQ*s_dots[ti][4+n] + b_post[g*4+n]);
      unsafeAtomicAdd(ws + OFF_ACCHP + tok*4 + n, hp);
    }
    if (lane<16){
      float m = expf(aR*s_dots[ti][8+lane] + b_res[g*16+lane]);
      for (int itr=0; itr<6; ++itr){
        float rsum = m;
        rsum += __shfl_xor(rsum, 1, 4);
        rsum += __shfl_xor(rsum, 2, 4);
        m = m / rsum;
        float csum = m;
        csum += __shfl_xor(csum, 4, 16);
        csum += __shfl_xor(csum, 8, 16);
        m = m / csum;
      }
      unsafeAtomicAdd(ws + OFF_ACCRES + tok*16 + lane, m);
    }
    float he[8]; float ssp = 0.f;
    #pragma unroll
    for (int m=0;m<8;++m){
      int d = m*32+lane;
      float hv = fmaf(g3, sbx[3*262144+d], fmaf(g2, sbx[2*262144+d], fmaf(g1, sbx[262144+d], g0*sbx[d])));
      he[m]=hv; ssp = fmaf(hv,hv,ssp);
    }
    ssp += __shfl_xor(ssp,16,32); ssp += __shfl_xor(ssp,8,32); ssp += __shfl_xor(ssp,4,32);
    ssp += __shfl_xor(ssp,2,32);  ssp += __shfl_xor(ssp,1,32);
    float scale = (float)(1.0/sqrt((double)(ssp*(1.0f/256.0f)+1e-6f)));
    float* hg = ws + OFF_HEKV + ((size_t)h*BT_ + tok)*256;
    #pragma unroll
    for (int m=0;m<8;++m){
      int d = m*32+lane;
      hg[d] = he[m]*scale*s_gnw[d];
    }
  };
  finish(ti0, tok0, dA0, sb0);
  finish(ti1, tok1, dA1, sb1);
}

// ---------------- K2b: he for q-selected tokens ----------------
__global__ __launch_bounds__(256) void k_he_q(
    const float* __restrict__ stream, float* ws,
    const float* __restrict__ mhc_norm_w, const float* __restrict__ phi_pre,
    const float* __restrict__ b_pre, const float* __restrict__ a_pre,
    const float* __restrict__ norm_w)
{
  int g = blockIdx.y; int h = g>>2;
  const int* cnt = (const int*)ws;
  int c = cnt[32+g];
  int start = blockIdx.x*TBH;
  if (start >= c) return;
  int nact = min(TBH, c-start);

  __shared__ float s_nw[1024];
  __shared__ float s_gnw[256];
  __shared__ int s_tok[TBH];
  int tid = threadIdx.x;
  if (tid < TBH) s_tok[tid] = (tid<nact) ? ((const int*)(ws + OFF_LQ))[g*BT_ + start + tid] : -1;
  for (int i=tid;i<1024;i+=256) s_nw[i] = mhc_norm_w[g*1024+i];
  s_gnw[tid] = norm_w[g*256+tid];
  __syncthreads();
  float aP = a_pre[g];
  int hw = tid>>5, lane = tid&31;

  for (int ii=0; ii<2; ++ii){
    int ti = hw + ii*8;
    int tok = s_tok[ti];
    if (tok < 0) continue;
    int b = tok>>10, t = tok&1023;
    const float* sb = stream + ((size_t)b*4*1024 + (size_t)t)*256;
    float rms = ws[OFF_RMS + tok];
    const float4* ppre = (const float4*)(phi_pre + (size_t)g*4096);
    float d0=0.f,d1=0.f,d2=0.f,d3=0.f;
    #pragma unroll 4
    for (int j=0;j<32;++j){
      int k = j*32 + lane;
      float xv = sb[(size_t)(k>>8)*262144 + (k&255)] * rms * s_nw[k];
      float4 pa = ppre[k];
      d0=fmaf(xv,pa.x,d0); d1=fmaf(xv,pa.y,d1); d2=fmaf(xv,pa.z,d2); d3=fmaf(xv,pa.w,d3);
    }
    d0 += __shfl_xor(d0,16,32); d0 += __shfl_xor(d0,8,32); d0 += __shfl_xor(d0,4,32); d0 += __shfl_xor(d0,2,32); d0 += __shfl_xor(d0,1,32);
    d1 += __shfl_xor(d1,16,32); d1 += __shfl_xor(d1,8,32); d1 += __shfl_xor(d1,4,32); d1 += __shfl_xor(d1,2,32); d1 += __shfl_xor(d1,1,32);
    d2 += __shfl_xor(d2,16,32); d2 += __shfl_xor(d2,8,32); d2 += __shfl_xor(d2,4,32); d2 += __shfl_xor(d2,2,32); d2 += __shfl_xor(d2,1,32);
    d3 += __shfl_xor(d3,16,32); d3 += __shfl_xor(d3,8,32); d3 += __shfl_xor(d3,4,32); d3 += __shfl_xor(d3,2,32); d3 += __shfl_xor(d3,1,32);
    float g0 = sigf(aP*d0+b_pre[g*4+0]);
    float g1 = sigf(aP*d1+b_pre[g*4+1]);
    float g2 = sigf(aP*d2+b_pre[g*4+2]);
    float g3 = sigf(aP*d3+b_pre[g*4+3]);
    float he[8]; float ssp = 0.f;
    #pragma unroll
    for (int m=0;m<8;++m){
      int d = m*32+lane;
      float hv = fmaf(g3, sb[3*262144+d], fmaf(g2, sb[2*262144+d], fmaf(g1, sb[262144+d], g0*sb[d])));
      he[m]=hv; ssp = fmaf(hv,hv,ssp);
    }
    ssp += __shfl_xor(ssp,16,32); ssp += __shfl_xor(ssp,8,32); ssp += __shfl_xor(ssp,4,32);
    ssp += __shfl_xor(ssp,2,32);  ssp += __shfl_xor(ssp,1,32);
    float scale = (float)(1.0/sqrt((double)(ssp*(1.0f/256.0f)+1e-6f)));
    float* hg = ws + OFF_HEQ + ((size_t)h*BT_ + tok)*256;
    #pragma unroll
    for (int m=0;m<8;++m){
      int d = m*32+lane;
      hg[d] = he[m]*scale*s_gnw[d];
    }
  }
}

// ---------------- K3a: kv projections (pure GEMM streaming) ----------------
__global__ __launch_bounds__(512,4) void k_proj_kv(
    float* ws,
    const float* __restrict__ Wk, const float* __restrict__ Wv,
    const float* __restrict__ lora_A_k, const float* __restrict__ lora_B_k,
    const float* __restrict__ lora_A_v, const float* __restrict__ lora_B_v,
    const float* __restrict__ alpha_up, const float* __restrict__ alpha_down,
    const float* __restrict__ beta_up, const float* __restrict__ beta_down,
    const float* __restrict__ W_pre)
{
  int g = blockIdx.y; int h = g>>2;
  const int* cnt = (const int*)ws;
  int c = cnt[g];
  int start = blockIdx.x*TB;
  if (start >= c) return;
  int nact = min(TB, c-start);

  __shared__ float s_he[TB][260];
  __shared__ float s_lrk[TB][4];
  __shared__ float s_lrv[TB][4];
  __shared__ float s_au[TB][25];
  __shared__ float s_bu[TB][25];
  __shared__ int s_tok[TB];
  int tid = threadIdx.x;
  if (tid < TB) s_tok[tid] = (tid < nact) ? ((const int*)(ws + OFF_LKV))[g*BT_ + start + tid] : -1;
  __syncthreads();
  for (int i=tid; i<TB*64; i+=512){
    int row=i>>6, c4=i&63;
    int tok = s_tok[row];
    float4 v = {0.f,0.f,0.f,0.f};
    if (tok>=0) v = ((const float4*)(ws + OFF_HEKV + ((size_t)h*BT_ + tok)*256))[c4];
    *(float4*)(&s_he[row][c4*4]) = v;
  }
  __syncthreads();

  // lora A (k and v): 256 threads
  if (tid < 256){
    int tt = (tid & 127) >> 2, r = tid & 3;
    const float* A = (tid < 128 ? lora_A_k : lora_A_v) + g*1024 + r;
    float acc = 0.f;
    for (int dd=0; dd<256; ++dd) acc = fmaf(s_he[tt][dd], A[dd*4], acc);
    float sv = siluf(acc);
    if (tid<128) s_lrk[tt][r] = sv; else s_lrv[tt][r] = sv;
  }
  __syncthreads();
  // k path + pope: 512 = 32 tok x 16 cols
  {
    int tt = tid>>4, kk = tid&15;
    float acc=0.f;
    const float* Wkp = Wk + h*4096 + kk;
    for (int dd=0; dd<256; ++dd) acc = fmaf(s_he[tt][dd], Wkp[dd*16], acc);
    float dkv = 0.f;
    for (int r=0;r<4;r++) dkv = fmaf(s_lrk[tt][r], lora_B_k[g*64 + r*16 + kk], dkv);
    acc += dkv;
    float ssq = acc*acc;
    ssq += __shfl_xor(ssq, 1, 16);
    ssq += __shfl_xor(ssq, 2, 16);
    ssq += __shfl_xor(ssq, 4, 16);
    ssq += __shfl_xor(ssq, 8, 16);
    float den = fmaxf(sqrtf(ssq), 1e-12f);
    float xn = acc/den;
    float mu = softplusf(xn);
    if (tt < nact){
      int tok = s_tok[tt]; int t = tok&1023;
      float* kh = ws + OFF_KH + ((size_t)h*BT_ + tok)*32;
      const float* ck = ws + OFF_TRIG + 32768;
      const float* sk = ws + OFF_TRIG + 49152;
      kh[kk]    = mu*ck[t*16+kk];
      kh[16+kk] = mu*sk[t*16+kk];
    }
  }
  // v path: 4 passes, 512 = 8 tok x 64 cols
  for (int pass=0; pass<4; ++pass){
    int tt = pass*8 + (tid>>6), col = tid&63;
    float acc=0.f;
    const float* Wvp = Wv + h*16384 + col;
    for (int dd=0; dd<256; ++dd) acc = fmaf(s_he[tt][dd], Wvp[dd*64], acc);
    for (int r=0;r<4;r++) acc = fmaf(s_lrv[tt][r], lora_B_v[g*256 + r*64 + col], acc);
    if (tt < nact)
      ws[OFF_VH + ((size_t)h*BT_ + s_tok[tt])*64 + col] = siluf(acc);
  }
  // alpha_up / beta_up
  for (int idx = tid; idx < nact*25; idx += 512){
    int tt = idx/25, aa = idx%25;
    const float* Au = alpha_up + g*6400 + aa;
    float acc=0.f;
    for (int dd=0; dd<256; ++dd) acc = fmaf(s_he[tt][dd], Au[dd*25], acc);
    s_au[tt][aa] = siluf(acc);
    const float* Bu = beta_up + g*6400 + aa;
    float acc2=0.f;
    for (int dd=0; dd<256; ++dd) acc2 = fmaf(s_he[tt][dd], Bu[dd*25], acc2);
    s_bu[tt][aa] = siluf(acc2);
  }
  __syncthreads();
  // alpha_down
  for (int idx = tid; idx < nact*32; idx += 512){
    int tt = idx>>5, kk = idx&31;
    float acc=0.f;
    for (int aa=0; aa<25; ++aa) acc = fmaf(s_au[tt][aa], alpha_down[g*800 + aa*32 + kk], acc);
    ws[OFF_ALH + ((size_t)h*BT_ + s_tok[tt])*32 + kk] = sigf(acc);
  }
  // beta_down
  if (tid < nact){
    float acc=0.f;
    for (int aa=0; aa<25; ++aa) acc = fmaf(s_bu[tid][aa], beta_down[g*25+aa], acc);
    ws[OFF_BEH + (size_t)h*BT_ + s_tok[tid]] = sigf(acc);
  }
  // W_pre: thread = column (512), acc over 32 tokens
  {
    float acc[TB];
    #pragma unroll
    for (int tt=0;tt<TB;++tt) acc[tt]=0.f;
    const float* Wp = W_pre + (size_t)g*131072 + tid;
    for (int dd=0; dd<256; ++dd){
      float w = Wp[(size_t)dd*512];
      #pragma unroll
      for (int tt=0;tt<TB;++tt) acc[tt] = fmaf(s_he[tt][dd], w, acc[tt]);
    }
    for (int tt=0;tt<nact;++tt)
      unsafeAtomicAdd(ws + OFF_ACCPRE + (size_t)s_tok[tt]*512 + tid, siluf(acc[tt]));
  }
}

// ---------------- K3b: q projections ----------------
__global__ __launch_bounds__(512,4) void k_proj_q(
    float* ws,
    const float* __restrict__ Wq, const float* __restrict__ lora_A_q, const float* __restrict__ lora_B_q,
    const float* __restrict__ W_pg1, const float* __restrict__ W_pg2)
{
  int g = blockIdx.y; int h = g>>2;
  const int* cnt = (const int*)ws;
  int c = cnt[32+g];
  int start = blockIdx.x*TB;
  if (start >= c) return;
  int nact = min(TB, c-start);

  __shared__ float s_he[TB][260];
  __shared__ float s_u[TB][DPG_];
  __shared__ float s_lrq[TB][4];
  __shared__ int s_tok[TB];
  int tid = threadIdx.x;
  if (tid < TB) s_tok[tid] = (tid<nact) ? ((const int*)(ws + OFF_LQ))[g*BT_ + start + tid] : -1;
  __syncthreads();
  for (int i=tid; i<TB*64; i+=512){
    int row=i>>6, c4=i&63;
    int tok = s_tok[row];
    float4 v = {0.f,0.f,0.f,0.f};
    if (tok>=0) v = ((const float4*)(ws + OFF_HEQ + ((size_t)h*BT_ + tok)*256))[c4];
    *(float4*)(&s_he[row][c4*4]) = v;
  }
  __syncthreads();

  // lora q: 128 threads
  if (tid<128){
    int tt=tid>>2, r=tid&3;
    const float* A = lora_A_q + g*1024 + r;
    float acc=0.f;
    for (int dd=0;dd<256;++dd) acc = fmaf(s_he[tt][dd], A[dd*4], acc);
    s_lrq[tt][r] = siluf(acc);
  }
  __syncthreads();
  // q + pope
  {
    int tt=tid>>4, kk=tid&15;
    const float* Wqp = Wq + h*4096 + kk;
    float acc=0.f;
    for (int dd=0;dd<256;++dd) acc = fmaf(s_he[tt][dd], Wqp[dd*16], acc);
    float dq=0.f;
    for (int r=0;r<4;r++) dq = fmaf(s_lrq[tt][r], lora_B_q[g*64+r*16+kk], dq);
    acc += dq;
    float ssq = acc*acc;
    ssq += __shfl_xor(ssq,1,16); ssq += __shfl_xor(ssq,2,16);
    ssq += __shfl_xor(ssq,4,16); ssq += __shfl_xor(ssq,8,16);
    float den = fmaxf(sqrtf(ssq),1e-12f);
    float xn = acc/den;
    float mu = softplusf(xn);
    if (tt<nact){
      int tok=s_tok[tt]; int t=tok&1023;
      float* qh = ws + OFF_QH + ((size_t)h*BT_+tok)*32;
      const float* cq = ws + OFF_TRIG;
      const float* sq = ws + OFF_TRIG + 16384;
      qh[kk]    = mu*cq[t*16+kk];
      qh[16+kk] = mu*sq[t*16+kk];
    }
  }
  // W_pg1: thread = column (tid<316), acc over 32 tokens
  if (tid < DPG_){
    float acc[TB];
    #pragma unroll
    for (int tt=0;tt<TB;++tt) acc[tt]=0.f;
    const float* Wp = W_pg1 + (size_t)g*80896 + tid;
    for (int dd=0;dd<256;++dd){
      float w = Wp[(size_t)dd*316];
      #pragma unroll
      for (int tt=0;tt<TB;++tt) acc[tt] = fmaf(s_he[tt][dd], w, acc[tt]);
    }
    #pragma unroll
    for (int tt=0;tt<TB;++tt) s_u[tt][tid] = siluf(acc[tt]);
  }
  __syncthreads();
  // W_pg2: 512 = 2 token-halves x 256 cols
  {
    int half = tid>>8, col = tid&255;
    float acc2[16];
    #pragma unroll
    for (int j=0;j<16;++j) acc2[j]=0.f;
    const float* Wp2 = W_pg2 + (size_t)g*80896 + col;
    for (int p=0;p<DPG_;++p){
      float w = Wp2[(size_t)p*256];
      #pragma unroll
      for (int j=0;j<16;++j) acc2[j] = fmaf(s_u[half*16+j][p], w, acc2[j]);
    }
    #pragma unroll
    for (int j=0;j<16;++j){
      int tt = half*16 + j;
      if (tt < nact)
        unsafeAtomicAdd(ws + OFF_ACCPOST + (size_t)s_tok[tt]*256 + col, sigf(acc2[j]));
    }
  }
}

// ---------------- K4: KDA delta-rule recurrence ----------------
__global__ __launch_bounds__(256) void k_kda(float* ws){
  int hb = blockIdx.x; int h = hb>>2, b = hb&3;
  int tid = threadIdx.x;
  int e = tid >> 2, dg = tid & 3;
  const float* qb = ws + OFF_QH  + ((size_t)h*BT_ + b*T_)*32;
  const float* kb = ws + OFF_KH  + ((size_t)h*BT_ + b*T_)*32;
  const float* ab = ws + OFF_ALH + ((size_t)h*BT_ + b*T_)*32;
  const float* vb = ws + OFF_VH  + ((size_t)h*BT_ + b*T_)*64;
  const float* bb = ws + OFF_BEH + (size_t)h*BT_ + b*T_;
  float* ob = ws + OFF_ATTN + (size_t)b*T_*512 + h*64;

  __shared__ float s_q[TT*32];
  __shared__ float s_k[TT*32];
  __shared__ float s_a[TT*32];
  __shared__ float s_v[TT*64];
  __shared__ float s_b[TT];
  __shared__ float s_o[TT*64];

  float S[8];
  #pragma unroll
  for (int j=0;j<8;++j) S[j]=0.f;

  for (int t0=0; t0<T_; t0+=TT){
    {
      const float4* q4 = (const float4*)(qb + t0*32);
      const float4* k4 = (const float4*)(kb + t0*32);
      const float4* a4 = (const float4*)(ab + t0*32);
      const float4* v4 = (const float4*)(vb + t0*64);
      #pragma unroll
      for (int r=0;r<2;++r){
        int i = r*256 + tid;
        ((float4*)s_q)[i] = q4[i];
        ((float4*)s_k)[i] = k4[i];
        ((float4*)s_a)[i] = a4[i];
      }
      #pragma unroll
      for (int r=0;r<4;++r){
        int i = r*256 + tid;
        ((float4*)s_v)[i] = v4[i];
      }
      if (tid < TT) s_b[tid] = bb[t0+tid];
    }
    __syncthreads();
    #pragma unroll 4
    for (int tt=0; tt<TT; ++tt){
      const float* kp = s_k + tt*32 + dg*8;
      const float* ap = s_a + tt*32 + dg*8;
      const float* qp = s_q + tt*32 + dg*8;
      float v  = s_v[tt*64 + e];
      float be = s_b[tt];
      float part = 0.f;
      float kv[8], av[8];
      #pragma unroll
      for (int j=0;j<8;++j){ kv[j]=kp[j]; av[j]=ap[j]; part = fmaf(kv[j]*av[j], S[j], part); }
      part += __shfl_xor(part, 1, 4);
      part += __shfl_xor(part, 2, 4);
      float w = be*(v - part);
      float op = 0.f;
      #pragma unroll
      for (int j=0;j<8;++j){
        S[j] = fmaf(w, kv[j], av[j]*S[j]);
        op = fmaf(qp[j], S[j], op);
      }
      op += __shfl_xor(op, 1, 4);
      op += __shfl_xor(op, 2, 4);
      if (dg==0) s_o[tt*64 + e] = op / 22.627416997969522f;
    }
    __syncthreads();
    for (int i=tid; i<TT*16; i+=256){
      int tt = i>>4, c = i&15;
      ((float4*)(ob + (size_t)(t0+tt)*512))[c] = ((const float4*)(s_o + tt*64))[c];
    }
  }
}

// ---------------- K5: W_o epilogue + stream mixing ----------------
__global__ __launch_bounds__(256) void k_final(const float* __restrict__ stream,
    const float* __restrict__ W_o, float* ws, float* __restrict__ out){
  __shared__ float s_m[8][512];
  __shared__ float s_rs[8][16];
  __shared__ float s_hp[8][4];
  int tid = threadIdx.x;
  int t0 = blockIdx.x*8;
  for (int tt=0;tt<8;++tt){
    int tok = t0+tt;
    for (int idx=tid; idx<512; idx+=256)
      s_m[tt][idx] = ws[OFF_ATTN + (size_t)tok*512 + idx] * (0.125f*ws[OFF_ACCPRE + (size_t)tok*512 + idx]);
    if (tid<16) s_rs[tt][tid] = 0.125f*ws[OFF_ACCRES + tok*16 + tid];
    if (tid<4)  s_hp[tt][tid] = 0.125f*ws[OFF_ACCHP + tok*4 + tid];
  }
  __syncthreads();
  float facc[8];
  #pragma unroll
  for (int tt=0;tt<8;++tt) facc[tt]=0.f;
  const float* Wop = W_o + tid;
  for (int cc=0;cc<512;++cc){
    float w = Wop[(size_t)cc*256];
    #pragma unroll
    for (int tt=0;tt<8;++tt) facc[tt] = fmaf(s_m[tt][cc], w, facc[tt]);
  }
  for (int tt=0;tt<8;++tt){
    int tok=t0+tt; int b=tok>>10, t=tok&1023;
    float result = facc[tt]*(0.125f*ws[OFF_ACCPOST + (size_t)tok*256 + tid]);
    float st[4];
    #pragma unroll
    for (int j=0;j<4;++j) st[j]=stream[(((size_t)b*4+j)*1024+t)*256+tid];
    #pragma unroll
    for (int n=0;n<4;++n){
      float rv = fmaf(s_rs[tt][n*4+3], st[3],
                 fmaf(s_rs[tt][n*4+2], st[2],
                 fmaf(s_rs[tt][n*4+1], st[1], s_rs[tt][n*4]*st[0])));
      out[(((size_t)b*4+n)*1024+t)*256+tid] = rv + s_hp[tt][n]*result;
    }
  }
}

extern "C" void kernel_launch(void* const* d_in, const int* in_sizes, int n_in,
                              void* d_out, int out_size, void* d_ws, size_t ws_size,
                              hipStream_t stream){
  const float* s = (const float*)d_in[0];
  float* ws = (float*)d_ws;
  hipMemsetAsync(d_ws, 0, (size_t)ZERO_END*4, stream);
  k_trig<<<64,256,0,stream>>>((const float*)d_in[4], ws);
  k_route<<<4096,256,0,stream>>>(s, (const float*)d_in[5], (const float*)d_in[6], ws);
  dim3 gh(BT_/TBH, 32);
  k_he_kv<<<gh,256,0,stream>>>(s, ws,
      (const float*)d_in[17], (const float*)d_in[18],
      (const float*)d_in[19], (const float*)d_in[20],
      (const float*)d_in[21], (const float*)d_in[22], (const float*)d_in[23],
      (const float*)d_in[24], (const float*)d_in[25], (const float*)d_in[26],
      (const float*)d_in[27]);
  k_he_q<<<gh,256,0,stream>>>(s, ws,
      (const float*)d_in[17], (const float*)d_in[18],
      (const float*)d_in[21], (const float*)d_in[24],
      (const float*)d_in[27]);
  dim3 gp(BT_/TB, 32);
  k_proj_kv<<<gp,512,0,stream>>>(ws,
      (const float*)d_in[2],  (const float*)d_in[3],
      (const float*)d_in[9],  (const float*)d_in[10],
      (const float*)d_in[11], (const float*)d_in[12],
      (const float*)d_in[13], (const float*)d_in[14],
      (const float*)d_in[15], (const float*)d_in[16],
      (const float*)d_in[28]);
  k_proj_q<<<gp,512,0,stream>>>(ws,
      (const float*)d_in[1],  (const float*)d_in[7], (const float*)d_in[8],
      (const float*)d_in[30], (const float*)d_in[31]);
  k_kda<<<32,256,0,stream>>>(ws);
  k_final<<<512,256,0,stream>>>(s, (const float*)d_in[29], ws, (float*)d_out);
}

// Round 8
// 1352.681 us; speedup vs baseline: 1.3064x; 1.3064x over previous
//
#include <hip/hip_runtime.h>
#include <math.h>

#define B_ 4
#define NM 4
#define T_ 1024
#define D_ 256
#define DK_ 16
#define DV_ 64
#define DKP_ 32
#define H_ 8
#define E_ 4
#define HE_ 32
#define R_ 4
#define DA_ 25
#define DPG_ 316
#define ND_ 1024
#define DATTN_ 512
#define BT_ 4096
#define TBH 16
#define TB 32
#define TT 64

// ---- workspace layout (float offsets) ----
#define OFF_CNT     0                          // 64 ints: cnt_kv[32], cnt_q[32]
#define OFF_ACCPRE  256                        // BT*512
#define OFF_ACCPOST (OFF_ACCPRE + BT_*512)     // BT*256
#define OFF_ACCRES  (OFF_ACCPOST + BT_*256)    // BT*16
#define OFF_ACCHP   (OFF_ACCRES + BT_*16)      // BT*4
#define OFF_QH      (OFF_ACCHP + BT_*4)        // H*BT*32 (zeroed: unselected q stays 0)
#define ZERO_END    (OFF_QH + H_*BT_*32)
#define OFF_KH      ZERO_END                   // H*BT*32
#define OFF_VH      (OFF_KH + H_*BT_*32)       // H*BT*64
#define OFF_ALH     (OFF_VH + H_*BT_*64)      // H*BT*32
#define OFF_BEH     (OFF_ALH + H_*BT_*32)      // H*BT
#define OFF_LKV     (OFF_BEH + H_*BT_)         // 32*BT ints
#define OFF_LQ      (OFF_LKV + HE_*BT_)        // 32*BT ints
#define OFF_RMS     (OFF_LQ + HE_*BT_)         // BT
#define OFF_ATTN    (OFF_RMS + BT_)            // BT*512
#define OFF_TRIG    (OFF_ATTN + BT_*512)       // 4*T*DK
#define OFF_HEKV    (OFF_TRIG + 4*T_*DK_)      // H*BT*256
#define OFF_HEQ     (OFF_HEKV + H_*BT_*256)    // H*BT*256
#define WS_FLOATS   (OFF_HEQ + H_*BT_*256)

__device__ __forceinline__ float sigf(float x){ return 1.0f/(1.0f+expf(-x)); }
__device__ __forceinline__ float siluf(float x){ return x/(1.0f+expf(-x)); }
__device__ __forceinline__ float softplusf(float x){ return fmaxf(x,0.0f)+log1pf(expf(-fabsf(x))); }

// ---------------- K0: trig tables ----------------
__global__ __launch_bounds__(256) void k_trig(const float* __restrict__ delta, float* __restrict__ ws){
  int idx = blockIdx.x*256 + threadIdx.x;
  int t = idx >> 4, k = idx & 15;
  double fr = pow(10000.0, (double)k / 16.0);
  float freq = (float)fr;
  float pq = (float)t * freq;
  float sg = sigf(delta[k]);
  float shift = (float)(2.0*M_PI) * sg;
  float pk = pq - shift;
  float* tr = ws + OFF_TRIG;
  tr[idx]         = (float)cos((double)pq);
  tr[16384+idx]   = (float)sin((double)pq);
  tr[32768+idx]   = (float)cos((double)pk);
  tr[49152+idx]   = (float)sin((double)pk);
}

// ---------------- K1: RMS scale + routing + gather lists ----------------
__global__ __launch_bounds__(256) void k_route(const float* __restrict__ stream,
    const float* __restrict__ q_router, const float* __restrict__ kv_router,
    float* __restrict__ ws){
  __shared__ float s_route[256];
  __shared__ float s_red[4];
  __shared__ float s_log[64];
  int tok = blockIdx.x; int b = tok >> 10, t = tok & 1023;
  int d = threadIdx.x;
  const float* sp = stream + ((size_t)(b*4)*1024 + t)*256 + d;
  float s0 = sp[0];
  float s1 = sp[1024*256];
  float s2 = sp[2*1024*256];
  float s3 = sp[3*1024*256];
  s_route[d] = (((s0+s1)+s2)+s3)*0.25f;
  float ssp = s0*s0+s1*s1+s2*s2+s3*s3;
  for (int off=32; off; off>>=1) ssp += __shfl_xor(ssp, off, 64);
  if ((d & 63)==0) s_red[d>>6] = ssp;
  __syncthreads();
  if (d==0){
    float ss = ((s_red[0]+s_red[1])+s_red[2])+s_red[3];
    float mean = ss*(1.0f/1024.0f) + 1e-6f;
    ws[OFF_RMS + tok] = (float)(1.0/sqrt((double)mean));
  }
  if (d < 64){
    int lane = d;
    int r = lane>>5, h = (lane>>2)&7, e = lane&3;
    const float* R = (r ? kv_router : q_router) + h*1024 + e;
    float acc = 0.f;
    for (int dd=0; dd<256; ++dd) acc = fmaf(s_route[dd], R[dd*4], acc);
    s_log[lane] = fminf(fmaxf(acc,-10.f),10.f);
  }
  if (d < 16){
    int r = d>>3, h = d&7;
    int base = r*32 + h*4;
    int best=0; float bv = s_log[base];
    for (int e=1;e<4;e++){ float v=s_log[base+e]; if (v>bv){bv=v;best=e;} }
    int* cnt = (int*)ws;
    if (r==1){
      int* lst = (int*)(ws + OFF_LKV);
      int pos = atomicAdd(&cnt[h*4+best],1);
      lst[(h*4+best)*BT_ + pos] = tok;
    } else if (best>0){
      int* lst = (int*)(ws + OFF_LQ);
      int pos = atomicAdd(&cnt[32 + h*4+best],1);
      lst[(h*4+best)*BT_ + pos] = tok;
    }
  }
}

// ---------------- K2a: he for kv-selected tokens ----------------
__global__ __launch_bounds__(256) void k_he_kv(
    const float* __restrict__ stream, float* ws,
    const float* __restrict__ mhc_norm_w, const float* __restrict__ phi_pre,
    const float* __restrict__ phi_post, const float* __restrict__ phi_res,
    const float* __restrict__ b_pre, const float* __restrict__ b_post, const float* __restrict__ b_res,
    const float* __restrict__ a_pre, const float* __restrict__ a_post, const float* __restrict__ a_res,
    const float* __restrict__ norm_w)
{
  int g = blockIdx.y; int h = g>>2;
  const int* cnt = (const int*)ws;
  int c = cnt[g];
  int start = blockIdx.x*TBH;
  if (start >= c) return;
  int nact = min(TBH, c-start);

  __shared__ float s_phi[24][128];
  __shared__ float s_dots[TBH][24];
  __shared__ float s_nw[1024];
  __shared__ float s_gnw[256];
  __shared__ int s_tok[TBH];
  int tid = threadIdx.x;
  if (tid < TBH) s_tok[tid] = (tid < nact) ? ((const int*)(ws + OFF_LKV))[g*BT_ + start + tid] : -1;
  for (int i=tid;i<1024;i+=256) s_nw[i] = mhc_norm_w[g*1024+i];
  s_gnw[tid] = norm_w[g*256+tid];
  __syncthreads();

  float aP = a_pre[g], aQ = a_post[g], aR = a_res[g];
  int hw = tid>>5, lane = tid&31;
  int ti0 = hw, ti1 = hw+8;
  int tok0 = s_tok[ti0], tok1 = s_tok[ti1];
  const float* sb0 = stream + (tok0>=0 ? ((size_t)(tok0>>10)*4*262144 + (size_t)(tok0&1023)*256) : 0);
  const float* sb1 = stream + (tok1>=0 ? ((size_t)(tok1>>10)*4*262144 + (size_t)(tok1&1023)*256) : 0);
  float rn0 = (tok0>=0) ? ws[OFF_RMS + tok0] : 0.f;
  float rn1 = (tok1>=0) ? ws[OFF_RMS + tok1] : 0.f;

  float dA0[24], dA1[24];
  #pragma unroll
  for (int n=0;n<24;++n){ dA0[n]=0.f; dA1[n]=0.f; }
  for (int cc=0; cc<8; ++cc){
    __syncthreads();
    {
      int kk = tid & 127;
      int np = tid >> 7;
      int kg = cc*128 + kk;
      #pragma unroll
      for (int it=0; it<12; ++it){
        int n = np + it*2;
        float v;
        if (n < 4)       v = phi_pre [(size_t)g*4096  + (size_t)kg*4  + n];
        else if (n < 8)  v = phi_post[(size_t)g*4096  + (size_t)kg*4  + (n-4)];
        else             v = phi_res [(size_t)g*16384 + (size_t)kg*16 + (n-8)];
        s_phi[n][kk] = v;
      }
    }
    __syncthreads();
    int rr = cc>>1;
    int off = (cc&1)*128 + lane*4;
    float4 x0 = *(const float4*)(sb0 + (size_t)rr*262144 + off);
    float4 x1 = *(const float4*)(sb1 + (size_t)rr*262144 + off);
    float4 nw4 = *(const float4*)(&s_nw[cc*128 + lane*4]);
    x0.x *= rn0*nw4.x; x0.y *= rn0*nw4.y; x0.z *= rn0*nw4.z; x0.w *= rn0*nw4.w;
    x1.x *= rn1*nw4.x; x1.y *= rn1*nw4.y; x1.z *= rn1*nw4.z; x1.w *= rn1*nw4.w;
    #pragma unroll
    for (int n=0;n<24;++n){
      float4 p4 = *(const float4*)(&s_phi[n][lane*4]);
      dA0[n] = fmaf(x0.w,p4.w,fmaf(x0.z,p4.z,fmaf(x0.y,p4.y,fmaf(x0.x,p4.x,dA0[n]))));
      dA1[n] = fmaf(x1.w,p4.w,fmaf(x1.z,p4.z,fmaf(x1.y,p4.y,fmaf(x1.x,p4.x,dA1[n]))));
    }
  }
  #pragma unroll
  for (int n=0;n<24;++n){
    float v0=dA0[n], v1=dA1[n];
    v0 += __shfl_xor(v0,16,32); v0 += __shfl_xor(v0,8,32); v0 += __shfl_xor(v0,4,32); v0 += __shfl_xor(v0,2,32); v0 += __shfl_xor(v0,1,32);
    v1 += __shfl_xor(v1,16,32); v1 += __shfl_xor(v1,8,32); v1 += __shfl_xor(v1,4,32); v1 += __shfl_xor(v1,2,32); v1 += __shfl_xor(v1,1,32);
    dA0[n]=v0; dA1[n]=v1;
  }
  float bp0=b_pre[g*4+0], bp1=b_pre[g*4+1], bp2=b_pre[g*4+2], bp3=b_pre[g*4+3];

  auto finish = [&](int ti, int tok, const float (&dAx)[24], const float* sbx){
    if (tok < 0) return;
    if (lane==0){
      #pragma unroll
      for (int n=0;n<24;++n) s_dots[ti][n] = dAx[n];
    }
    float g0 = sigf(aP*dAx[0]+bp0);
    float g1 = sigf(aP*dAx[1]+bp1);
    float g2 = sigf(aP*dAx[2]+bp2);
    float g3 = sigf(aP*dAx[3]+bp3);
    if (lane>=16 && lane<20){
      int n = lane-16;
      float hp = 2.f*sigf(aQ*s_dots[ti][4+n] + b_post[g*4+n]);
      unsafeAtomicAdd(ws + OFF_ACCHP + tok*4 + n, hp);
    }
    if (lane<16){
      float m = expf(aR*s_dots[ti][8+lane] + b_res[g*16+lane]);
      for (int itr=0; itr<6; ++itr){
        float rsum = m;
        rsum += __shfl_xor(rsum, 1, 4);
        rsum += __shfl_xor(rsum, 2, 4);
        m = m / rsum;
        float csum = m;
        csum += __shfl_xor(csum, 4, 16);
        csum += __shfl_xor(csum, 8, 16);
        m = m / csum;
      }
      unsafeAtomicAdd(ws + OFF_ACCRES + tok*16 + lane, m);
    }
    float he[8]; float ssp = 0.f;
    #pragma unroll
    for (int m=0;m<8;++m){
      int d = m*32+lane;
      float hv = fmaf(g3, sbx[3*262144+d], fmaf(g2, sbx[2*262144+d], fmaf(g1, sbx[262144+d], g0*sbx[d])));
      he[m]=hv; ssp = fmaf(hv,hv,ssp);
    }
    ssp += __shfl_xor(ssp,16,32); ssp += __shfl_xor(ssp,8,32); ssp += __shfl_xor(ssp,4,32);
    ssp += __shfl_xor(ssp,2,32);  ssp += __shfl_xor(ssp,1,32);
    float scale = (float)(1.0/sqrt((double)(ssp*(1.0f/256.0f)+1e-6f)));
    float* hg = ws + OFF_HEKV + ((size_t)h*BT_ + tok)*256;
    #pragma unroll
    for (int m=0;m<8;++m){
      int d = m*32+lane;
      hg[d] = he[m]*scale*s_gnw[d];
    }
  };
  finish(ti0, tok0, dA0, sb0);
  finish(ti1, tok1, dA1, sb1);
}

// ---------------- K2b: he for q-selected tokens ----------------
__global__ __launch_bounds__(256) void k_he_q(
    const float* __restrict__ stream, float* ws,
    const float* __restrict__ mhc_norm_w, const float* __restrict__ phi_pre,
    const float* __restrict__ b_pre, const float* __restrict__ a_pre,
    const float* __restrict__ norm_w)
{
  int g = blockIdx.y; int h = g>>2;
  const int* cnt = (const int*)ws;
  int c = cnt[32+g];
  int start = blockIdx.x*TBH;
  if (start >= c) return;
  int nact = min(TBH, c-start);

  __shared__ float s_nw[1024];
  __shared__ float s_gnw[256];
  __shared__ int s_tok[TBH];
  int tid = threadIdx.x;
  if (tid < TBH) s_tok[tid] = (tid<nact) ? ((const int*)(ws + OFF_LQ))[g*BT_ + start + tid] : -1;
  for (int i=tid;i<1024;i+=256) s_nw[i] = mhc_norm_w[g*1024+i];
  s_gnw[tid] = norm_w[g*256+tid];
  __syncthreads();
  float aP = a_pre[g];
  int hw = tid>>5, lane = tid&31;

  for (int ii=0; ii<2; ++ii){
    int ti = hw + ii*8;
    int tok = s_tok[ti];
    if (tok < 0) continue;
    int b = tok>>10, t = tok&1023;
    const float* sb = stream + ((size_t)b*4*1024 + (size_t)t)*256;
    float rms = ws[OFF_RMS + tok];
    const float4* ppre = (const float4*)(phi_pre + (size_t)g*4096);
    float d0=0.f,d1=0.f,d2=0.f,d3=0.f;
    #pragma unroll 4
    for (int j=0;j<32;++j){
      int k = j*32 + lane;
      float xv = sb[(size_t)(k>>8)*262144 + (k&255)] * rms * s_nw[k];
      float4 pa = ppre[k];
      d0=fmaf(xv,pa.x,d0); d1=fmaf(xv,pa.y,d1); d2=fmaf(xv,pa.z,d2); d3=fmaf(xv,pa.w,d3);
    }
    d0 += __shfl_xor(d0,16,32); d0 += __shfl_xor(d0,8,32); d0 += __shfl_xor(d0,4,32); d0 += __shfl_xor(d0,2,32); d0 += __shfl_xor(d0,1,32);
    d1 += __shfl_xor(d1,16,32); d1 += __shfl_xor(d1,8,32); d1 += __shfl_xor(d1,4,32); d1 += __shfl_xor(d1,2,32); d1 += __shfl_xor(d1,1,32);
    d2 += __shfl_xor(d2,16,32); d2 += __shfl_xor(d2,8,32); d2 += __shfl_xor(d2,4,32); d2 += __shfl_xor(d2,2,32); d2 += __shfl_xor(d2,1,32);
    d3 += __shfl_xor(d3,16,32); d3 += __shfl_xor(d3,8,32); d3 += __shfl_xor(d3,4,32); d3 += __shfl_xor(d3,2,32); d3 += __shfl_xor(d3,1,32);
    float g0 = sigf(aP*d0+b_pre[g*4+0]);
    float g1 = sigf(aP*d1+b_pre[g*4+1]);
    float g2 = sigf(aP*d2+b_pre[g*4+2]);
    float g3 = sigf(aP*d3+b_pre[g*4+3]);
    float he[8]; float ssp = 0.f;
    #pragma unroll
    for (int m=0;m<8;++m){
      int d = m*32+lane;
      float hv = fmaf(g3, sb[3*262144+d], fmaf(g2, sb[2*262144+d], fmaf(g1, sb[262144+d], g0*sb[d])));
      he[m]=hv; ssp = fmaf(hv,hv,ssp);
    }
    ssp += __shfl_xor(ssp,16,32); ssp += __shfl_xor(ssp,8,32); ssp += __shfl_xor(ssp,4,32);
    ssp += __shfl_xor(ssp,2,32);  ssp += __shfl_xor(ssp,1,32);
    float scale = (float)(1.0/sqrt((double)(ssp*(1.0f/256.0f)+1e-6f)));
    float* hg = ws + OFF_HEQ + ((size_t)h*BT_ + tok)*256;
    #pragma unroll
    for (int m=0;m<8;++m){
      int d = m*32+lane;
      hg[d] = he[m]*scale*s_gnw[d];
    }
  }
}

// ---------------- K3a: kv projections (register-tiled GEMM) ----------------
__global__ __launch_bounds__(512,2) void k_proj_kv(
    float* ws,
    const float* __restrict__ Wk, const float* __restrict__ Wv,
    const float* __restrict__ lora_A_k, const float* __restrict__ lora_B_k,
    const float* __restrict__ lora_A_v, const float* __restrict__ lora_B_v,
    const float* __restrict__ alpha_up, const float* __restrict__ alpha_down,
    const float* __restrict__ beta_up, const float* __restrict__ beta_down,
    const float* __restrict__ W_pre)
{
  int g = blockIdx.y; int h = g>>2;
  const int* cnt = (const int*)ws;
  int c = cnt[g];
  int start = blockIdx.x*TB;
  if (start >= c) return;
  int nact = min(TB, c-start);

  __shared__ float s_he[TB][260];
  __shared__ float s_lrk[TB][4];
  __shared__ float s_lrv[TB][4];
  __shared__ float s_au[TB][25];
  __shared__ float s_bu[TB][25];
  __shared__ int s_tok[TB];
  int tid = threadIdx.x;
  if (tid < TB) s_tok[tid] = (tid < nact) ? ((const int*)(ws + OFF_LKV))[g*BT_ + start + tid] : -1;
  __syncthreads();
  for (int i=tid; i<TB*64; i+=512){
    int row=i>>6, c4=i&63;
    int tok = s_tok[row];
    float4 v = {0.f,0.f,0.f,0.f};
    if (tok>=0) v = ((const float4*)(ws + OFF_HEKV + ((size_t)h*BT_ + tok)*256))[c4];
    *(float4*)(&s_he[row][c4*4]) = v;
  }
  __syncthreads();

  // lora A (k and v): 256 threads
  if (tid < 256){
    int tt = (tid & 127) >> 2, r = tid & 3;
    const float* A = (tid < 128 ? lora_A_k : lora_A_v) + g*1024 + r;
    float acc = 0.f;
    for (int dd=0; dd<256; dd+=4){
      float4 h4 = *(const float4*)(&s_he[tt][dd]);
      acc = fmaf(h4.x, A[(dd+0)*4], fmaf(h4.y, A[(dd+1)*4], fmaf(h4.z, A[(dd+2)*4], fmaf(h4.w, A[(dd+3)*4], acc))));
    }
    float sv = siluf(acc);
    if (tid<128) s_lrk[tt][r] = sv; else s_lrv[tt][r] = sv;
  }
  __syncthreads();
  // k path + pope: 512 = 32 tok x 16 cols, dd vectorized
  {
    int tt = tid>>4, kk = tid&15;
    const float* Wkp = Wk + h*4096 + kk;
    float acc=0.f;
    for (int dd=0; dd<256; dd+=4){
      float4 h4 = *(const float4*)(&s_he[tt][dd]);
      acc = fmaf(h4.x, Wkp[(dd+0)*16], fmaf(h4.y, Wkp[(dd+1)*16], fmaf(h4.z, Wkp[(dd+2)*16], fmaf(h4.w, Wkp[(dd+3)*16], acc))));
    }
    float dkv = 0.f;
    for (int r=0;r<4;r++) dkv = fmaf(s_lrk[tt][r], lora_B_k[g*64 + r*16 + kk], dkv);
    acc += dkv;
    float ssq = acc*acc;
    ssq += __shfl_xor(ssq, 1, 16);
    ssq += __shfl_xor(ssq, 2, 16);
    ssq += __shfl_xor(ssq, 4, 16);
    ssq += __shfl_xor(ssq, 8, 16);
    float den = fmaxf(sqrtf(ssq), 1e-12f);
    float xn = acc/den;
    float mu = softplusf(xn);
    if (tt < nact){
      int tok = s_tok[tt]; int t = tok&1023;
      float* kh = ws + OFF_KH + ((size_t)h*BT_ + tok)*32;
      const float* ck = ws + OFF_TRIG + 32768;
      const float* sk = ws + OFF_TRIG + 49152;
      kh[kk]    = mu*ck[t*16+kk];
      kh[16+kk] = mu*sk[t*16+kk];
    }
  }
  // v path: thread = (tg: 4 tokens) x (col: 64), dd vectorized
  {
    int col = tid & 63;
    int tg = tid >> 6;
    const float* Wvp = Wv + h*16384 + col;
    float vacc[4] = {0.f,0.f,0.f,0.f};
    for (int dd=0; dd<256; dd+=4){
      float w0 = Wvp[(dd+0)*64], w1 = Wvp[(dd+1)*64], w2 = Wvp[(dd+2)*64], w3 = Wvp[(dd+3)*64];
      #pragma unroll
      for (int j=0;j<4;++j){
        float4 h4 = *(const float4*)(&s_he[tg*4+j][dd]);
        vacc[j] = fmaf(h4.x,w0,fmaf(h4.y,w1,fmaf(h4.z,w2,fmaf(h4.w,w3,vacc[j]))));
      }
    }
    #pragma unroll
    for (int j=0;j<4;++j){
      int tt = tg*4+j;
      float a = vacc[j];
      for (int r=0;r<4;r++) a = fmaf(s_lrv[tt][r], lora_B_v[g*256 + r*64 + col], a);
      if (tt < nact)
        ws[OFF_VH + ((size_t)h*BT_ + s_tok[tt])*64 + col] = siluf(a);
    }
  }
  // alpha_up / beta_up: thread = (tg: 4 tokens) x (c: 50 cols au|bu)
  {
    int cc = tid & 63;
    int tg = tid >> 6;
    if (cc < 50){
      const float* Wab = (cc < 25) ? (alpha_up + g*6400 + cc) : (beta_up + g*6400 + (cc-25));
      float aacc[4] = {0.f,0.f,0.f,0.f};
      for (int dd=0; dd<256; dd+=4){
        float w0 = Wab[(dd+0)*25], w1 = Wab[(dd+1)*25], w2 = Wab[(dd+2)*25], w3 = Wab[(dd+3)*25];
        #pragma unroll
        for (int j=0;j<4;++j){
          float4 h4 = *(const float4*)(&s_he[tg*4+j][dd]);
          aacc[j] = fmaf(h4.x,w0,fmaf(h4.y,w1,fmaf(h4.z,w2,fmaf(h4.w,w3,aacc[j]))));
        }
      }
      #pragma unroll
      for (int j=0;j<4;++j){
        int tt = tg*4+j;
        float sv = siluf(aacc[j]);
        if (cc<25) s_au[tt][cc] = sv; else s_bu[tt][cc-25] = sv;
      }
    }
  }
  __syncthreads();
  // alpha_down
  for (int idx = tid; idx < nact*32; idx += 512){
    int tt = idx>>5, kk = idx&31;
    float acc=0.f;
    for (int aa=0; aa<25; ++aa) acc = fmaf(s_au[tt][aa], alpha_down[g*800 + aa*32 + kk], acc);
    ws[OFF_ALH + ((size_t)h*BT_ + s_tok[tt])*32 + kk] = sigf(acc);
  }
  // beta_down
  if (tid < nact){
    float acc=0.f;
    for (int aa=0; aa<25; ++aa) acc = fmaf(s_bu[tid][aa], beta_down[g*25+aa], acc);
    ws[OFF_BEH + (size_t)h*BT_ + s_tok[tid]] = sigf(acc);
  }
  // W_pre: register-tiled 8 tok x 4 cols per thread, dd vectorized by 4
  {
    int c4 = tid & 127;
    int tr = tid >> 7;
    float acc[8][4];
    #pragma unroll
    for (int j=0;j<8;++j){ acc[j][0]=0.f; acc[j][1]=0.f; acc[j][2]=0.f; acc[j][3]=0.f; }
    const float* Wp = W_pre + (size_t)g*131072 + 4*c4;
    for (int dd=0; dd<256; dd+=4){
      float4 w0 = *(const float4*)(Wp + (size_t)(dd+0)*512);
      float4 w1 = *(const float4*)(Wp + (size_t)(dd+1)*512);
      float4 w2 = *(const float4*)(Wp + (size_t)(dd+2)*512);
      float4 w3 = *(const float4*)(Wp + (size_t)(dd+3)*512);
      #pragma unroll
      for (int j=0;j<8;++j){
        float4 h4 = *(const float4*)(&s_he[tr*8+j][dd]);
        acc[j][0] = fmaf(h4.x,w0.x,fmaf(h4.y,w1.x,fmaf(h4.z,w2.x,fmaf(h4.w,w3.x,acc[j][0]))));
        acc[j][1] = fmaf(h4.x,w0.y,fmaf(h4.y,w1.y,fmaf(h4.z,w2.y,fmaf(h4.w,w3.y,acc[j][1]))));
        acc[j][2] = fmaf(h4.x,w0.z,fmaf(h4.y,w1.z,fmaf(h4.z,w2.z,fmaf(h4.w,w3.z,acc[j][2]))));
        acc[j][3] = fmaf(h4.x,w0.w,fmaf(h4.y,w1.w,fmaf(h4.z,w2.w,fmaf(h4.w,w3.w,acc[j][3]))));
      }
    }
    #pragma unroll
    for (int j=0;j<8;++j){
      int tt = tr*8+j;
      if (tt < nact){
        float* dst = ws + OFF_ACCPRE + (size_t)s_tok[tt]*512 + 4*c4;
        unsafeAtomicAdd(dst+0, siluf(acc[j][0]));
        unsafeAtomicAdd(dst+1, siluf(acc[j][1]));
        unsafeAtomicAdd(dst+2, siluf(acc[j][2]));
        unsafeAtomicAdd(dst+3, siluf(acc[j][3]));
      }
    }
  }
}

// ---------------- K3b: q projections (register-tiled GEMM) ----------------
__global__ __launch_bounds__(512,2) void k_proj_q(
    float* ws,
    const float* __restrict__ Wq, const float* __restrict__ lora_A_q, const float* __restrict__ lora_B_q,
    const float* __restrict__ W_pg1, const float* __restrict__ W_pg2)
{
  int g = blockIdx.y; int h = g>>2;
  const int* cnt = (const int*)ws;
  int c = cnt[32+g];
  int start = blockIdx.x*TB;
  if (start >= c) return;
  int nact = min(TB, c-start);

  __shared__ float s_he[TB][260];
  __shared__ float s_u[TB][DPG_];
  __shared__ float s_lrq[TB][4];
  __shared__ int s_tok[TB];
  int tid = threadIdx.x;
  if (tid < TB) s_tok[tid] = (tid<nact) ? ((const int*)(ws + OFF_LQ))[g*BT_ + start + tid] : -1;
  __syncthreads();
  for (int i=tid; i<TB*64; i+=512){
    int row=i>>6, c4=i&63;
    int tok = s_tok[row];
    float4 v = {0.f,0.f,0.f,0.f};
    if (tok>=0) v = ((const float4*)(ws + OFF_HEQ + ((size_t)h*BT_ + tok)*256))[c4];
    *(float4*)(&s_he[row][c4*4]) = v;
  }
  __syncthreads();

  // lora q: 128 threads
  if (tid<128){
    int tt=tid>>2, r=tid&3;
    const float* A = lora_A_q + g*1024 + r;
    float acc=0.f;
    for (int dd=0;dd<256;dd+=4){
      float4 h4 = *(const float4*)(&s_he[tt][dd]);
      acc = fmaf(h4.x, A[(dd+0)*4], fmaf(h4.y, A[(dd+1)*4], fmaf(h4.z, A[(dd+2)*4], fmaf(h4.w, A[(dd+3)*4], acc))));
    }
    s_lrq[tt][r] = siluf(acc);
  }
  __syncthreads();
  // q + pope
  {
    int tt=tid>>4, kk=tid&15;
    const float* Wqp = Wq + h*4096 + kk;
    float acc=0.f;
    for (int dd=0;dd<256;dd+=4){
      float4 h4 = *(const float4*)(&s_he[tt][dd]);
      acc = fmaf(h4.x, Wqp[(dd+0)*16], fmaf(h4.y, Wqp[(dd+1)*16], fmaf(h4.z, Wqp[(dd+2)*16], fmaf(h4.w, Wqp[(dd+3)*16], acc))));
    }
    float dq=0.f;
    for (int r=0;r<4;r++) dq = fmaf(s_lrq[tt][r], lora_B_q[g*64+r*16+kk], dq);
    acc += dq;
    float ssq = acc*acc;
    ssq += __shfl_xor(ssq,1,16); ssq += __shfl_xor(ssq,2,16);
    ssq += __shfl_xor(ssq,4,16); ssq += __shfl_xor(ssq,8,16);
    float den = fmaxf(sqrtf(ssq),1e-12f);
    float xn = acc/den;
    float mu = softplusf(xn);
    if (tt<nact){
      int tok=s_tok[tt]; int t=tok&1023;
      float* qh = ws + OFF_QH + ((size_t)h*BT_+tok)*32;
      const float* cq = ws + OFF_TRIG;
      const float* sq = ws + OFF_TRIG + 16384;
      qh[kk]    = mu*cq[t*16+kk];
      qh[16+kk] = mu*sq[t*16+kk];
    }
  }
  // W_pg1: register-tiled 8 tok x 4 cols (c4 < 79 covers 316 cols)
  {
    int c4 = tid & 127;
    int tr = tid >> 7;
    if (c4 < 79){
      float acc[8][4];
      #pragma unroll
      for (int j=0;j<8;++j){ acc[j][0]=0.f; acc[j][1]=0.f; acc[j][2]=0.f; acc[j][3]=0.f; }
      const float* Wp = W_pg1 + (size_t)g*80896 + 4*c4;
      for (int dd=0; dd<256; dd+=4){
        float4 w0 = *(const float4*)(Wp + (size_t)(dd+0)*316);
        float4 w1 = *(const float4*)(Wp + (size_t)(dd+1)*316);
        float4 w2 = *(const float4*)(Wp + (size_t)(dd+2)*316);
        float4 w3 = *(const float4*)(Wp + (size_t)(dd+3)*316);
        #pragma unroll
        for (int j=0;j<8;++j){
          float4 h4 = *(const float4*)(&s_he[tr*8+j][dd]);
          acc[j][0] = fmaf(h4.x,w0.x,fmaf(h4.y,w1.x,fmaf(h4.z,w2.x,fmaf(h4.w,w3.x,acc[j][0]))));
          acc[j][1] = fmaf(h4.x,w0.y,fmaf(h4.y,w1.y,fmaf(h4.z,w2.y,fmaf(h4.w,w3.y,acc[j][1]))));
          acc[j][2] = fmaf(h4.x,w0.z,fmaf(h4.y,w1.z,fmaf(h4.z,w2.z,fmaf(h4.w,w3.z,acc[j][2]))));
          acc[j][3] = fmaf(h4.x,w0.w,fmaf(h4.y,w1.w,fmaf(h4.z,w2.w,fmaf(h4.w,w3.w,acc[j][3]))));
        }
      }
      #pragma unroll
      for (int j=0;j<8;++j){
        int tt = tr*8+j;
        s_u[tt][4*c4+0] = siluf(acc[j][0]);
        s_u[tt][4*c4+1] = siluf(acc[j][1]);
        s_u[tt][4*c4+2] = siluf(acc[j][2]);
        s_u[tt][4*c4+3] = siluf(acc[j][3]);
      }
    }
  }
  __syncthreads();
  // W_pg2: register-tiled 8 tok x 2 cols, p vectorized by 4 (316 = 79*4)
  {
    int c2 = tid & 127;
    int tr = tid >> 7;
    float acc[8][2];
    #pragma unroll
    for (int j=0;j<8;++j){ acc[j][0]=0.f; acc[j][1]=0.f; }
    const float* Wp2 = W_pg2 + (size_t)g*80896 + 2*c2;
    for (int p=0; p<DPG_; p+=4){
      float2 w0 = *(const float2*)(Wp2 + (size_t)(p+0)*256);
      float2 w1 = *(const float2*)(Wp2 + (size_t)(p+1)*256);
      float2 w2 = *(const float2*)(Wp2 + (size_t)(p+2)*256);
      float2 w3 = *(const float2*)(Wp2 + (size_t)(p+3)*256);
      #pragma unroll
      for (int j=0;j<8;++j){
        float4 u4 = *(const float4*)(&s_u[tr*8+j][p]);
        acc[j][0] = fmaf(u4.x,w0.x,fmaf(u4.y,w1.x,fmaf(u4.z,w2.x,fmaf(u4.w,w3.x,acc[j][0]))));
        acc[j][1] = fmaf(u4.x,w0.y,fmaf(u4.y,w1.y,fmaf(u4.z,w2.y,fmaf(u4.w,w3.y,acc[j][1]))));
      }
    }
    #pragma unroll
    for (int j=0;j<8;++j){
      int tt = tr*8+j;
      if (tt < nact){
        float* dst = ws + OFF_ACCPOST + (size_t)s_tok[tt]*256 + 2*c2;
        unsafeAtomicAdd(dst+0, sigf(acc[j][0]));
        unsafeAtomicAdd(dst+1, sigf(acc[j][1]));
      }
    }
  }
}

// ---------------- K4: KDA delta-rule recurrence ----------------
__global__ __launch_bounds__(256) void k_kda(float* ws){
  int hb = blockIdx.x; int h = hb>>2, b = hb&3;
  int tid = threadIdx.x;
  int e = tid >> 2, dg = tid & 3;
  const float* qb = ws + OFF_QH  + ((size_t)h*BT_ + b*T_)*32;
  const float* kb = ws + OFF_KH  + ((size_t)h*BT_ + b*T_)*32;
  const float* ab = ws + OFF_ALH + ((size_t)h*BT_ + b*T_)*32;
  const float* vb = ws + OFF_VH  + ((size_t)h*BT_ + b*T_)*64;
  const float* bb = ws + OFF_BEH + (size_t)h*BT_ + b*T_;
  float* ob = ws + OFF_ATTN + (size_t)b*T_*512 + h*64;

  __shared__ float s_q[TT*32];
  __shared__ float s_k[TT*32];
  __shared__ float s_a[TT*32];
  __shared__ float s_v[TT*64];
  __shared__ float s_b[TT];
  __shared__ float s_o[TT*64];

  float S[8];
  #pragma unroll
  for (int j=0;j<8;++j) S[j]=0.f;

  for (int t0=0; t0<T_; t0+=TT){
    {
      const float4* q4 = (const float4*)(qb + t0*32);
      const float4* k4 = (const float4*)(kb + t0*32);
      const float4* a4 = (const float4*)(ab + t0*32);
      const float4* v4 = (const float4*)(vb + t0*64);
      #pragma unroll
      for (int r=0;r<2;++r){
        int i = r*256 + tid;
        ((float4*)s_q)[i] = q4[i];
        ((float4*)s_k)[i] = k4[i];
        ((float4*)s_a)[i] = a4[i];
      }
      #pragma unroll
      for (int r=0;r<4;++r){
        int i = r*256 + tid;
        ((float4*)s_v)[i] = v4[i];
      }
      if (tid < TT) s_b[tid] = bb[t0+tid];
    }
    __syncthreads();
    #pragma unroll 4
    for (int tt=0; tt<TT; ++tt){
      const float* kp = s_k + tt*32 + dg*8;
      const float* ap = s_a + tt*32 + dg*8;
      const float* qp = s_q + tt*32 + dg*8;
      float v  = s_v[tt*64 + e];
      float be = s_b[tt];
      float part = 0.f;
      float kv[8], av[8];
      #pragma unroll
      for (int j=0;j<8;++j){ kv[j]=kp[j]; av[j]=ap[j]; part = fmaf(kv[j]*av[j], S[j], part); }
      part += __shfl_xor(part, 1, 4);
      part += __shfl_xor(part, 2, 4);
      float w = be*(v - part);
      float op = 0.f;
      #pragma unroll
      for (int j=0;j<8;++j){
        S[j] = fmaf(w, kv[j], av[j]*S[j]);
        op = fmaf(qp[j], S[j], op);
      }
      op += __shfl_xor(op, 1, 4);
      op += __shfl_xor(op, 2, 4);
      if (dg==0) s_o[tt*64 + e] = op / 22.627416997969522f;
    }
    __syncthreads();
    for (int i=tid; i<TT*16; i+=256){
      int tt = i>>4, c = i&15;
      ((float4*)(ob + (size_t)(t0+tt)*512))[c] = ((const float4*)(s_o + tt*64))[c];
    }
  }
}

// ---------------- K5: W_o epilogue + stream mixing ----------------
__global__ __launch_bounds__(256) void k_final(const float* __restrict__ stream,
    const float* __restrict__ W_o, float* ws, float* __restrict__ out){
  __shared__ float s_m[8][512];
  __shared__ float s_rs[8][16];
  __shared__ float s_hp[8][4];
  int tid = threadIdx.x;
  int t0 = blockIdx.x*8;
  for (int tt=0;tt<8;++tt){
    int tok = t0+tt;
    for (int idx=tid; idx<512; idx+=256)
      s_m[tt][idx] = ws[OFF_ATTN + (size_t)tok*512 + idx] * (0.125f*ws[OFF_ACCPRE + (size_t)tok*512 + idx]);
    if (tid<16) s_rs[tt][tid] = 0.125f*ws[OFF_ACCRES + tok*16 + tid];
    if (tid<4)  s_hp[tt][tid] = 0.125f*ws[OFF_ACCHP + tok*4 + tid];
  }
  __syncthreads();
  float facc[8];
  #pragma unroll
  for (int tt=0;tt<8;++tt) facc[tt]=0.f;
  const float* Wop = W_o + tid;
  for (int cc=0;cc<512;++cc){
    float w = Wop[(size_t)cc*256];
    #pragma unroll
    for (int tt=0;tt<8;++tt) facc[tt] = fmaf(s_m[tt][cc], w, facc[tt]);
  }
  for (int tt=0;tt<8;++tt){
    int tok=t0+tt; int b=tok>>10, t=tok&1023;
    float result = facc[tt]*(0.125f*ws[OFF_ACCPOST + (size_t)tok*256 + tid]);
    float st[4];
    #pragma unroll
    for (int j=0;j<4;++j) st[j]=stream[(((size_t)b*4+j)*1024+t)*256+tid];
    #pragma unroll
    for (int n=0;n<4;++n){
      float rv = fmaf(s_rs[tt][n*4+3], st[3],
                 fmaf(s_rs[tt][n*4+2], st[2],
                 fmaf(s_rs[tt][n*4+1], st[1], s_rs[tt][n*4]*st[0])));
      out[(((size_t)b*4+n)*1024+t)*256+tid] = rv + s_hp[tt][n]*result;
    }
  }
}

extern "C" void kernel_launch(void* const* d_in, const int* in_sizes, int n_in,
                              void* d_out, int out_size, void* d_ws, size_t ws_size,
                              hipStream_t stream){
  const float* s = (const float*)d_in[0];
  float* ws = (float*)d_ws;
  hipMemsetAsync(d_ws, 0, (size_t)ZERO_END*4, stream);
  k_trig<<<64,256,0,stream>>>((const float*)d_in[4], ws);
  k_route<<<4096,256,0,stream>>>(s, (const float*)d_in[5], (const float*)d_in[6], ws);
  dim3 gh(BT_/TBH, 32);
  k_he_kv<<<gh,256,0,stream>>>(s, ws,
      (const float*)d_in[17], (const float*)d_in[18],
      (const float*)d_in[19], (const float*)d_in[20],
      (const float*)d_in[21], (const float*)d_in[22], (const float*)d_in[23],
      (const float*)d_in[24], (const float*)d_in[25], (const float*)d_in[26],
      (const float*)d_in[27]);
  k_he_q<<<gh,256,0,stream>>>(s, ws,
      (const float*)d_in[17], (const float*)d_in[18],
      (const float*)d_in[21], (const float*)d_in[24],
      (const float*)d_in[27]);
  dim3 gp(BT_/TB, 32);
  k_proj_kv<<<gp,512,0,stream>>>(ws,
      (const float*)d_in[2],  (const float*)d_in[3],
      (const float*)d_in[9],  (const float*)d_in[10],
      (const float*)d_in[11], (const float*)d_in[12],
      (const float*)d_in[13], (const float*)d_in[14],
      (const float*)d_in[15], (const float*)d_in[16],
      (const float*)d_in[28]);
  k_proj_q<<<gp,512,0,stream>>>(ws,
      (const float*)d_in[1],  (const float*)d_in[7], (const float*)d_in[8],
      (const float*)d_in[30], (const float*)d_in[31]);
  k_kda<<<32,256,0,stream>>>(ws);
  k_final<<<512,256,0,stream>>>(s, (const float*)d_in[29], ws, (float*)d_out);
}

// Round 10
// 1284.525 us; speedup vs baseline: 1.3757x; 1.0531x over previous
//
#include <hip/hip_runtime.h>
#include <math.h>

#define B_ 4
#define NM 4
#define T_ 1024
#define D_ 256
#define DK_ 16
#define DV_ 64
#define DKP_ 32
#define H_ 8
#define E_ 4
#define HE_ 32
#define R_ 4
#define DA_ 25
#define DPG_ 316
#define ND_ 1024
#define DATTN_ 512
#define BT_ 4096
#define TBH 16
#define TB 32
#define TT 64

// ---- workspace layout (float offsets) ----
#define OFF_CNT     0                          // 64 ints: cnt_kv[32], cnt_q[32]
#define OFF_ACCPRE  256                        // BT*512
#define OFF_ACCPOST (OFF_ACCPRE + BT_*512)     // BT*256
#define OFF_ACCRES  (OFF_ACCPOST + BT_*256)    // BT*16
#define OFF_ACCHP   (OFF_ACCRES + BT_*16)      // BT*4
#define OFF_QH      (OFF_ACCHP + BT_*4)        // H*BT*32 (zeroed: unselected q stays 0)
#define ZERO_END    (OFF_QH + H_*BT_*32)
#define OFF_KH      ZERO_END                   // H*BT*32
#define OFF_VH      (OFF_KH + H_*BT_*32)       // H*BT*64
#define OFF_ALH     (OFF_VH + H_*BT_*64)      // H*BT*32
#define OFF_BEH     (OFF_ALH + H_*BT_*32)      // H*BT
#define OFF_LKV     (OFF_BEH + H_*BT_)         // 32*BT ints
#define OFF_LQ      (OFF_LKV + HE_*BT_)        // 32*BT ints
#define OFF_RMS     (OFF_LQ + HE_*BT_)         // BT
#define OFF_ATTN    (OFF_RMS + BT_)            // BT*512
#define OFF_TRIG    (OFF_ATTN + BT_*512)       // 4*T*DK
#define OFF_HEKV    (OFF_TRIG + 4*T_*DK_)      // H*BT*256
#define OFF_HEQ     (OFF_HEKV + H_*BT_*256)    // H*BT*256
#define WS_FLOATS   (OFF_HEQ + H_*BT_*256)

__device__ __forceinline__ float sigf(float x){ return 1.0f/(1.0f+expf(-x)); }
__device__ __forceinline__ float siluf(float x){ return x/(1.0f+expf(-x)); }
__device__ __forceinline__ float softplusf(float x){ return fmaxf(x,0.0f)+log1pf(expf(-fabsf(x))); }

// ---------------- K0: trig tables ----------------
__global__ __launch_bounds__(256) void k_trig(const float* __restrict__ delta, float* __restrict__ ws){
  int idx = blockIdx.x*256 + threadIdx.x;
  int t = idx >> 4, k = idx & 15;
  double fr = pow(10000.0, (double)k / 16.0);
  float freq = (float)fr;
  float pq = (float)t * freq;
  float sg = sigf(delta[k]);
  float shift = (float)(2.0*M_PI) * sg;
  float pk = pq - shift;
  float* tr = ws + OFF_TRIG;
  tr[idx]         = (float)cos((double)pq);
  tr[16384+idx]   = (float)sin((double)pq);
  tr[32768+idx]   = (float)cos((double)pk);
  tr[49152+idx]   = (float)sin((double)pk);
}

// ---------------- K1: RMS scale + routing + gather lists ----------------
__global__ __launch_bounds__(256) void k_route(const float* __restrict__ stream,
    const float* __restrict__ q_router, const float* __restrict__ kv_router,
    float* __restrict__ ws){
  __shared__ float s_route[256];
  __shared__ float s_red[4];
  __shared__ float s_log[64];
  int tok = blockIdx.x; int b = tok >> 10, t = tok & 1023;
  int d = threadIdx.x;
  const float* sp = stream + ((size_t)(b*4)*1024 + t)*256 + d;
  float s0 = sp[0];
  float s1 = sp[1024*256];
  float s2 = sp[2*1024*256];
  float s3 = sp[3*1024*256];
  s_route[d] = (((s0+s1)+s2)+s3)*0.25f;
  float ssp = s0*s0+s1*s1+s2*s2+s3*s3;
  for (int off=32; off; off>>=1) ssp += __shfl_xor(ssp, off, 64);
  if ((d & 63)==0) s_red[d>>6] = ssp;
  __syncthreads();
  if (d==0){
    float ss = ((s_red[0]+s_red[1])+s_red[2])+s_red[3];
    float mean = ss*(1.0f/1024.0f) + 1e-6f;
    ws[OFF_RMS + tok] = (float)(1.0/sqrt((double)mean));
  }
  if (d < 64){
    int lane = d;
    int r = lane>>5, h = (lane>>2)&7, e = lane&3;
    const float* R = (r ? kv_router : q_router) + h*1024 + e;
    float acc = 0.f;
    for (int dd=0; dd<256; ++dd) acc = fmaf(s_route[dd], R[dd*4], acc);
    s_log[lane] = fminf(fmaxf(acc,-10.f),10.f);
  }
  if (d < 16){
    int r = d>>3, h = d&7;
    int base = r*32 + h*4;
    int best=0; float bv = s_log[base];
    for (int e=1;e<4;e++){ float v=s_log[base+e]; if (v>bv){bv=v;best=e;} }
    int* cnt = (int*)ws;
    if (r==1){
      int* lst = (int*)(ws + OFF_LKV);
      int pos = atomicAdd(&cnt[h*4+best],1);
      lst[(h*4+best)*BT_ + pos] = tok;
    } else if (best>0){
      int* lst = (int*)(ws + OFF_LQ);
      int pos = atomicAdd(&cnt[32 + h*4+best],1);
      lst[(h*4+best)*BT_ + pos] = tok;
    }
  }
}

// ---------------- K2a: he for kv-selected tokens ----------------
__global__ __launch_bounds__(256) void k_he_kv(
    const float* __restrict__ stream, float* ws,
    const float* __restrict__ mhc_norm_w, const float* __restrict__ phi_pre,
    const float* __restrict__ phi_post, const float* __restrict__ phi_res,
    const float* __restrict__ b_pre, const float* __restrict__ b_post, const float* __restrict__ b_res,
    const float* __restrict__ a_pre, const float* __restrict__ a_post, const float* __restrict__ a_res,
    const float* __restrict__ norm_w)
{
  int g = blockIdx.y; int h = g>>2;
  const int* cnt = (const int*)ws;
  int c = cnt[g];
  int start = blockIdx.x*TBH;
  if (start >= c) return;
  int nact = min(TBH, c-start);

  __shared__ float s_phi[24][128];
  __shared__ float s_dots[TBH][24];
  __shared__ float s_nw[1024];
  __shared__ float s_gnw[256];
  __shared__ int s_tok[TBH];
  int tid = threadIdx.x;
  if (tid < TBH) s_tok[tid] = (tid < nact) ? ((const int*)(ws + OFF_LKV))[g*BT_ + start + tid] : -1;
  for (int i=tid;i<1024;i+=256) s_nw[i] = mhc_norm_w[g*1024+i];
  s_gnw[tid] = norm_w[g*256+tid];
  __syncthreads();

  float aP = a_pre[g], aQ = a_post[g], aR = a_res[g];
  int hw = tid>>5, lane = tid&31;
  int ti0 = hw, ti1 = hw+8;
  int tok0 = s_tok[ti0], tok1 = s_tok[ti1];
  const float* sb0 = stream + (tok0>=0 ? ((size_t)(tok0>>10)*4*262144 + (size_t)(tok0&1023)*256) : 0);
  const float* sb1 = stream + (tok1>=0 ? ((size_t)(tok1>>10)*4*262144 + (size_t)(tok1&1023)*256) : 0);
  float rn0 = (tok0>=0) ? ws[OFF_RMS + tok0] : 0.f;
  float rn1 = (tok1>=0) ? ws[OFF_RMS + tok1] : 0.f;

  float dA0[24], dA1[24];
  #pragma unroll
  for (int n=0;n<24;++n){ dA0[n]=0.f; dA1[n]=0.f; }
  for (int cc=0; cc<8; ++cc){
    __syncthreads();
    {
      int kk = tid & 127;
      int np = tid >> 7;
      int kg = cc*128 + kk;
      #pragma unroll
      for (int it=0; it<12; ++it){
        int n = np + it*2;
        float v;
        if (n < 4)       v = phi_pre [(size_t)g*4096  + (size_t)kg*4  + n];
        else if (n < 8)  v = phi_post[(size_t)g*4096  + (size_t)kg*4  + (n-4)];
        else             v = phi_res [(size_t)g*16384 + (size_t)kg*16 + (n-8)];
        s_phi[n][kk] = v;
      }
    }
    __syncthreads();
    int rr = cc>>1;
    int off = (cc&1)*128 + lane*4;
    float4 x0 = *(const float4*)(sb0 + (size_t)rr*262144 + off);
    float4 x1 = *(const float4*)(sb1 + (size_t)rr*262144 + off);
    float4 nw4 = *(const float4*)(&s_nw[cc*128 + lane*4]);
    x0.x *= rn0*nw4.x; x0.y *= rn0*nw4.y; x0.z *= rn0*nw4.z; x0.w *= rn0*nw4.w;
    x1.x *= rn1*nw4.x; x1.y *= rn1*nw4.y; x1.z *= rn1*nw4.z; x1.w *= rn1*nw4.w;
    #pragma unroll
    for (int n=0;n<24;++n){
      float4 p4 = *(const float4*)(&s_phi[n][lane*4]);
      dA0[n] = fmaf(x0.w,p4.w,fmaf(x0.z,p4.z,fmaf(x0.y,p4.y,fmaf(x0.x,p4.x,dA0[n]))));
      dA1[n] = fmaf(x1.w,p4.w,fmaf(x1.z,p4.z,fmaf(x1.y,p4.y,fmaf(x1.x,p4.x,dA1[n]))));
    }
  }
  #pragma unroll
  for (int n=0;n<24;++n){
    float v0=dA0[n], v1=dA1[n];
    v0 += __shfl_xor(v0,16,32); v0 += __shfl_xor(v0,8,32); v0 += __shfl_xor(v0,4,32); v0 += __shfl_xor(v0,2,32); v0 += __shfl_xor(v0,1,32);
    v1 += __shfl_xor(v1,16,32); v1 += __shfl_xor(v1,8,32); v1 += __shfl_xor(v1,4,32); v1 += __shfl_xor(v1,2,32); v1 += __shfl_xor(v1,1,32);
    dA0[n]=v0; dA1[n]=v1;
  }
  float bp0=b_pre[g*4+0], bp1=b_pre[g*4+1], bp2=b_pre[g*4+2], bp3=b_pre[g*4+3];

  auto finish = [&](int ti, int tok, const float (&dAx)[24], const float* sbx){
    if (tok < 0) return;
    if (lane==0){
      #pragma unroll
      for (int n=0;n<24;++n) s_dots[ti][n] = dAx[n];
    }
    float g0 = sigf(aP*dAx[0]+bp0);
    float g1 = sigf(aP*dAx[1]+bp1);
    float g2 = sigf(aP*dAx[2]+bp2);
    float g3 = sigf(aP*dAx[3]+bp3);
    if (lane>=16 && lane<20){
      int n = lane-16;
      float hp = 2.f*sigf(aQ*s_dots[ti][4+n] + b_post[g*4+n]);
      unsafeAtomicAdd(ws + OFF_ACCHP + tok*4 + n, hp);
    }
    if (lane<16){
      float m = expf(aR*s_dots[ti][8+lane] + b_res[g*16+lane]);
      for (int itr=0; itr<6; ++itr){
        float rsum = m;
        rsum += __shfl_xor(rsum, 1, 4);
        rsum += __shfl_xor(rsum, 2, 4);
        m = m / rsum;
        float csum = m;
        csum += __shfl_xor(csum, 4, 16);
        csum += __shfl_xor(csum, 8, 16);
        m = m / csum;
      }
      unsafeAtomicAdd(ws + OFF_ACCRES + tok*16 + lane, m);
    }
    float he[8]; float ssp = 0.f;
    #pragma unroll
    for (int m=0;m<8;++m){
      int d = m*32+lane;
      float hv = fmaf(g3, sbx[3*262144+d], fmaf(g2, sbx[2*262144+d], fmaf(g1, sbx[262144+d], g0*sbx[d])));
      he[m]=hv; ssp = fmaf(hv,hv,ssp);
    }
    ssp += __shfl_xor(ssp,16,32); ssp += __shfl_xor(ssp,8,32); ssp += __shfl_xor(ssp,4,32);
    ssp += __shfl_xor(ssp,2,32);  ssp += __shfl_xor(ssp,1,32);
    float scale = (float)(1.0/sqrt((double)(ssp*(1.0f/256.0f)+1e-6f)));
    float* hg = ws + OFF_HEKV + ((size_t)h*BT_ + tok)*256;
    #pragma unroll
    for (int m=0;m<8;++m){
      int d = m*32+lane;
      hg[d] = he[m]*scale*s_gnw[d];
    }
  };
  finish(ti0, tok0, dA0, sb0);
  finish(ti1, tok1, dA1, sb1);
}

// ---------------- K2b: he for q-selected tokens ----------------
__global__ __launch_bounds__(256) void k_he_q(
    const float* __restrict__ stream, float* ws,
    const float* __restrict__ mhc_norm_w, const float* __restrict__ phi_pre,
    const float* __restrict__ b_pre, const float* __restrict__ a_pre,
    const float* __restrict__ norm_w)
{
  int g = blockIdx.y; int h = g>>2;
  const int* cnt = (const int*)ws;
  int c = cnt[32+g];
  int start = blockIdx.x*TBH;
  if (start >= c) return;
  int nact = min(TBH, c-start);

  __shared__ float s_nw[1024];
  __shared__ float s_gnw[256];
  __shared__ int s_tok[TBH];
  int tid = threadIdx.x;
  if (tid < TBH) s_tok[tid] = (tid<nact) ? ((const int*)(ws + OFF_LQ))[g*BT_ + start + tid] : -1;
  for (int i=tid;i<1024;i+=256) s_nw[i] = mhc_norm_w[g*1024+i];
  s_gnw[tid] = norm_w[g*256+tid];
  __syncthreads();
  float aP = a_pre[g];
  int hw = tid>>5, lane = tid&31;

  for (int ii=0; ii<2; ++ii){
    int ti = hw + ii*8;
    int tok = s_tok[ti];
    if (tok < 0) continue;
    int b = tok>>10, t = tok&1023;
    const float* sb = stream + ((size_t)b*4*1024 + (size_t)t)*256;
    float rms = ws[OFF_RMS + tok];
    const float4* ppre = (const float4*)(phi_pre + (size_t)g*4096);
    float d0=0.f,d1=0.f,d2=0.f,d3=0.f;
    #pragma unroll 4
    for (int j=0;j<32;++j){
      int k = j*32 + lane;
      float xv = sb[(size_t)(k>>8)*262144 + (k&255)] * rms * s_nw[k];
      float4 pa = ppre[k];
      d0=fmaf(xv,pa.x,d0); d1=fmaf(xv,pa.y,d1); d2=fmaf(xv,pa.z,d2); d3=fmaf(xv,pa.w,d3);
    }
    d0 += __shfl_xor(d0,16,32); d0 += __shfl_xor(d0,8,32); d0 += __shfl_xor(d0,4,32); d0 += __shfl_xor(d0,2,32); d0 += __shfl_xor(d0,1,32);
    d1 += __shfl_xor(d1,16,32); d1 += __shfl_xor(d1,8,32); d1 += __shfl_xor(d1,4,32); d1 += __shfl_xor(d1,2,32); d1 += __shfl_xor(d1,1,32);
    d2 += __shfl_xor(d2,16,32); d2 += __shfl_xor(d2,8,32); d2 += __shfl_xor(d2,4,32); d2 += __shfl_xor(d2,2,32); d2 += __shfl_xor(d2,1,32);
    d3 += __shfl_xor(d3,16,32); d3 += __shfl_xor(d3,8,32); d3 += __shfl_xor(d3,4,32); d3 += __shfl_xor(d3,2,32); d3 += __shfl_xor(d3,1,32);
    float g0 = sigf(aP*d0+b_pre[g*4+0]);
    float g1 = sigf(aP*d1+b_pre[g*4+1]);
    float g2 = sigf(aP*d2+b_pre[g*4+2]);
    float g3 = sigf(aP*d3+b_pre[g*4+3]);
    float he[8]; float ssp = 0.f;
    #pragma unroll
    for (int m=0;m<8;++m){
      int d = m*32+lane;
      float hv = fmaf(g3, sb[3*262144+d], fmaf(g2, sb[2*262144+d], fmaf(g1, sb[262144+d], g0*sb[d])));
      he[m]=hv; ssp = fmaf(hv,hv,ssp);
    }
    ssp += __shfl_xor(ssp,16,32); ssp += __shfl_xor(ssp,8,32); ssp += __shfl_xor(ssp,4,32);
    ssp += __shfl_xor(ssp,2,32);  ssp += __shfl_xor(ssp,1,32);
    float scale = (float)(1.0/sqrt((double)(ssp*(1.0f/256.0f)+1e-6f)));
    float* hg = ws + OFF_HEQ + ((size_t)h*BT_ + tok)*256;
    #pragma unroll
    for (int m=0;m<8;++m){
      int d = m*32+lane;
      hg[d] = he[m]*scale*s_gnw[d];
    }
  }
}

// ---------------- K3a: kv projections (register-tiled GEMM, coalesced atomics) ----------------
__global__ __launch_bounds__(512,2) void k_proj_kv(
    float* ws,
    const float* __restrict__ Wk, const float* __restrict__ Wv,
    const float* __restrict__ lora_A_k, const float* __restrict__ lora_B_k,
    const float* __restrict__ lora_A_v, const float* __restrict__ lora_B_v,
    const float* __restrict__ alpha_up, const float* __restrict__ alpha_down,
    const float* __restrict__ beta_up, const float* __restrict__ beta_down,
    const float* __restrict__ W_pre)
{
  int g = blockIdx.y; int h = g>>2;
  const int* cnt = (const int*)ws;
  int c = cnt[g];
  int start = blockIdx.x*TB;
  if (start >= c) return;
  int nact = min(TB, c-start);

  __shared__ float s_he[TB][260];
  __shared__ float s_lrk[TB][4];
  __shared__ float s_lrv[TB][4];
  __shared__ float s_au[TB][25];
  __shared__ float s_bu[TB][25];
  __shared__ int s_tok[TB];
  int tid = threadIdx.x;
  if (tid < TB) s_tok[tid] = (tid < nact) ? ((const int*)(ws + OFF_LKV))[g*BT_ + start + tid] : -1;
  __syncthreads();
  for (int i=tid; i<TB*64; i+=512){
    int row=i>>6, c4=i&63;
    int tok = s_tok[row];
    float4 v = {0.f,0.f,0.f,0.f};
    if (tok>=0) v = ((const float4*)(ws + OFF_HEKV + ((size_t)h*BT_ + tok)*256))[c4];
    *(float4*)(&s_he[row][c4*4]) = v;
  }
  __syncthreads();

  // lora A (k and v): 256 threads
  if (tid < 256){
    int tt = (tid & 127) >> 2, r = tid & 3;
    const float* A = (tid < 128 ? lora_A_k : lora_A_v) + g*1024 + r;
    float acc = 0.f;
    for (int dd=0; dd<256; dd+=4){
      float4 h4 = *(const float4*)(&s_he[tt][dd]);
      acc = fmaf(h4.x, A[(dd+0)*4], fmaf(h4.y, A[(dd+1)*4], fmaf(h4.z, A[(dd+2)*4], fmaf(h4.w, A[(dd+3)*4], acc))));
    }
    float sv = siluf(acc);
    if (tid<128) s_lrk[tt][r] = sv; else s_lrv[tt][r] = sv;
  }
  __syncthreads();
  // k path + pope: 512 = 32 tok x 16 cols, dd vectorized
  {
    int tt = tid>>4, kk = tid&15;
    const float* Wkp = Wk + h*4096 + kk;
    float acc=0.f;
    for (int dd=0; dd<256; dd+=4){
      float4 h4 = *(const float4*)(&s_he[tt][dd]);
      acc = fmaf(h4.x, Wkp[(dd+0)*16], fmaf(h4.y, Wkp[(dd+1)*16], fmaf(h4.z, Wkp[(dd+2)*16], fmaf(h4.w, Wkp[(dd+3)*16], acc))));
    }
    float dkv = 0.f;
    for (int r=0;r<4;r++) dkv = fmaf(s_lrk[tt][r], lora_B_k[g*64 + r*16 + kk], dkv);
    acc += dkv;
    float ssq = acc*acc;
    ssq += __shfl_xor(ssq, 1, 16);
    ssq += __shfl_xor(ssq, 2, 16);
    ssq += __shfl_xor(ssq, 4, 16);
    ssq += __shfl_xor(ssq, 8, 16);
    float den = fmaxf(sqrtf(ssq), 1e-12f);
    float xn = acc/den;
    float mu = softplusf(xn);
    if (tt < nact){
      int tok = s_tok[tt]; int t = tok&1023;
      float* kh = ws + OFF_KH + ((size_t)h*BT_ + tok)*32;
      const float* ck = ws + OFF_TRIG + 32768;
      const float* sk = ws + OFF_TRIG + 49152;
      kh[kk]    = mu*ck[t*16+kk];
      kh[16+kk] = mu*sk[t*16+kk];
    }
  }
  // v path: thread = (tg: 4 tokens) x (col: 64), dd vectorized
  {
    int col = tid & 63;
    int tg = tid >> 6;
    const float* Wvp = Wv + h*16384 + col;
    float vacc[4] = {0.f,0.f,0.f,0.f};
    for (int dd=0; dd<256; dd+=4){
      float w0 = Wvp[(dd+0)*64], w1 = Wvp[(dd+1)*64], w2 = Wvp[(dd+2)*64], w3 = Wvp[(dd+3)*64];
      #pragma unroll
      for (int j=0;j<4;++j){
        float4 h4 = *(const float4*)(&s_he[tg*4+j][dd]);
        vacc[j] = fmaf(h4.x,w0,fmaf(h4.y,w1,fmaf(h4.z,w2,fmaf(h4.w,w3,vacc[j]))));
      }
    }
    #pragma unroll
    for (int j=0;j<4;++j){
      int tt = tg*4+j;
      float a = vacc[j];
      for (int r=0;r<4;r++) a = fmaf(s_lrv[tt][r], lora_B_v[g*256 + r*64 + col], a);
      if (tt < nact)
        ws[OFF_VH + ((size_t)h*BT_ + s_tok[tt])*64 + col] = siluf(a);
    }
  }
  // alpha_up / beta_up: thread = (tg: 4 tokens) x (c: 50 cols au|bu)
  {
    int cc = tid & 63;
    int tg = tid >> 6;
    if (cc < 50){
      const float* Wab = (cc < 25) ? (alpha_up + g*6400 + cc) : (beta_up + g*6400 + (cc-25));
      float aacc[4] = {0.f,0.f,0.f,0.f};
      for (int dd=0; dd<256; dd+=4){
        float w0 = Wab[(dd+0)*25], w1 = Wab[(dd+1)*25], w2 = Wab[(dd+2)*25], w3 = Wab[(dd+3)*25];
        #pragma unroll
        for (int j=0;j<4;++j){
          float4 h4 = *(const float4*)(&s_he[tg*4+j][dd]);
          aacc[j] = fmaf(h4.x,w0,fmaf(h4.y,w1,fmaf(h4.z,w2,fmaf(h4.w,w3,aacc[j]))));
        }
      }
      #pragma unroll
      for (int j=0;j<4;++j){
        int tt = tg*4+j;
        float sv = siluf(aacc[j]);
        if (cc<25) s_au[tt][cc] = sv; else s_bu[tt][cc-25] = sv;
      }
    }
  }
  __syncthreads();
  // alpha_down
  for (int idx = tid; idx < nact*32; idx += 512){
    int tt = idx>>5, kk = idx&31;
    float acc=0.f;
    for (int aa=0; aa<25; ++aa) acc = fmaf(s_au[tt][aa], alpha_down[g*800 + aa*32 + kk], acc);
    ws[OFF_ALH + ((size_t)h*BT_ + s_tok[tt])*32 + kk] = sigf(acc);
  }
  // beta_down
  if (tid < nact){
    float acc=0.f;
    for (int aa=0; aa<25; ++aa) acc = fmaf(s_bu[tid][aa], beta_down[g*25+aa], acc);
    ws[OFF_BEH + (size_t)h*BT_ + s_tok[tid]] = sigf(acc);
  }
  // W_pre: 8 tok x 4 STRIDED cols per thread (cols c4, c4+128, c4+256, c4+384)
  // -> atomic writes are lane-consecutive (coalesced), weight loads wave-coalesced scalars
  {
    int c4 = tid & 127;
    int tr = tid >> 7;
    float acc[8][4];
    #pragma unroll
    for (int j=0;j<8;++j){ acc[j][0]=0.f; acc[j][1]=0.f; acc[j][2]=0.f; acc[j][3]=0.f; }
    const float* Wp = W_pre + (size_t)g*131072 + c4;
    for (int dd=0; dd<256; dd+=4){
      float w[4][4];
      #pragma unroll
      for (int r=0;r<4;++r){
        const float* Wr = Wp + (size_t)(dd+r)*512;
        w[r][0] = Wr[0]; w[r][1] = Wr[128]; w[r][2] = Wr[256]; w[r][3] = Wr[384];
      }
      #pragma unroll
      for (int j=0;j<8;++j){
        float4 h4 = *(const float4*)(&s_he[tr*8+j][dd]);
        #pragma unroll
        for (int q=0;q<4;++q)
          acc[j][q] = fmaf(h4.x,w[0][q],fmaf(h4.y,w[1][q],fmaf(h4.z,w[2][q],fmaf(h4.w,w[3][q],acc[j][q]))));
      }
    }
    #pragma unroll
    for (int j=0;j<8;++j){
      int tt = tr*8+j;
      if (tt < nact){
        float* dst = ws + OFF_ACCPRE + (size_t)s_tok[tt]*512 + c4;
        unsafeAtomicAdd(dst+0,   siluf(acc[j][0]));
        unsafeAtomicAdd(dst+128, siluf(acc[j][1]));
        unsafeAtomicAdd(dst+256, siluf(acc[j][2]));
        unsafeAtomicAdd(dst+384, siluf(acc[j][3]));
      }
    }
  }
}

// ---------------- K3b: q projections (register-tiled GEMM, coalesced atomics) ----------------
__global__ __launch_bounds__(512,2) void k_proj_q(
    float* ws,
    const float* __restrict__ Wq, const float* __restrict__ lora_A_q, const float* __restrict__ lora_B_q,
    const float* __restrict__ W_pg1, const float* __restrict__ W_pg2)
{
  int g = blockIdx.y; int h = g>>2;
  const int* cnt = (const int*)ws;
  int c = cnt[32+g];
  int start = blockIdx.x*TB;
  if (start >= c) return;
  int nact = min(TB, c-start);

  __shared__ float s_he[TB][260];
  __shared__ float s_u[TB][DPG_];
  __shared__ float s_lrq[TB][4];
  __shared__ int s_tok[TB];
  int tid = threadIdx.x;
  if (tid < TB) s_tok[tid] = (tid<nact) ? ((const int*)(ws + OFF_LQ))[g*BT_ + start + tid] : -1;
  __syncthreads();
  for (int i=tid; i<TB*64; i+=512){
    int row=i>>6, c4=i&63;
    int tok = s_tok[row];
    float4 v = {0.f,0.f,0.f,0.f};
    if (tok>=0) v = ((const float4*)(ws + OFF_HEQ + ((size_t)h*BT_ + tok)*256))[c4];
    *(float4*)(&s_he[row][c4*4]) = v;
  }
  __syncthreads();

  // lora q: 128 threads
  if (tid<128){
    int tt=tid>>2, r=tid&3;
    const float* A = lora_A_q + g*1024 + r;
    float acc=0.f;
    for (int dd=0;dd<256;dd+=4){
      float4 h4 = *(const float4*)(&s_he[tt][dd]);
      acc = fmaf(h4.x, A[(dd+0)*4], fmaf(h4.y, A[(dd+1)*4], fmaf(h4.z, A[(dd+2)*4], fmaf(h4.w, A[(dd+3)*4], acc))));
    }
    s_lrq[tt][r] = siluf(acc);
  }
  __syncthreads();
  // q + pope
  {
    int tt=tid>>4, kk=tid&15;
    const float* Wqp = Wq + h*4096 + kk;
    float acc=0.f;
    for (int dd=0;dd<256;dd+=4){
      float4 h4 = *(const float4*)(&s_he[tt][dd]);
      acc = fmaf(h4.x, Wqp[(dd+0)*16], fmaf(h4.y, Wqp[(dd+1)*16], fmaf(h4.z, Wqp[(dd+2)*16], fmaf(h4.w, Wqp[(dd+3)*16], acc))));
    }
    float dq=0.f;
    for (int r=0;r<4;r++) dq = fmaf(s_lrq[tt][r], lora_B_q[g*64+r*16+kk], dq);
    acc += dq;
    float ssq = acc*acc;
    ssq += __shfl_xor(ssq,1,16); ssq += __shfl_xor(ssq,2,16);
    ssq += __shfl_xor(ssq,4,16); ssq += __shfl_xor(ssq,8,16);
    float den = fmaxf(sqrtf(ssq),1e-12f);
    float xn = acc/den;
    float mu = softplusf(xn);
    if (tt<nact){
      int tok=s_tok[tt]; int t=tok&1023;
      float* qh = ws + OFF_QH + ((size_t)h*BT_+tok)*32;
      const float* cq = ws + OFF_TRIG;
      const float* sq = ws + OFF_TRIG + 16384;
      qh[kk]    = mu*cq[t*16+kk];
      qh[16+kk] = mu*sq[t*16+kk];
    }
  }
  // W_pg1: register-tiled 8 tok x 4 cols (c4 < 79 covers 316 cols), stores to LDS
  {
    int c4 = tid & 127;
    int tr = tid >> 7;
    if (c4 < 79){
      float acc[8][4];
      #pragma unroll
      for (int j=0;j<8;++j){ acc[j][0]=0.f; acc[j][1]=0.f; acc[j][2]=0.f; acc[j][3]=0.f; }
      const float* Wp = W_pg1 + (size_t)g*80896 + 4*c4;
      for (int dd=0; dd<256; dd+=4){
        float4 w0 = *(const float4*)(Wp + (size_t)(dd+0)*316);
        float4 w1 = *(const float4*)(Wp + (size_t)(dd+1)*316);
        float4 w2 = *(const float4*)(Wp + (size_t)(dd+2)*316);
        float4 w3 = *(const float4*)(Wp + (size_t)(dd+3)*316);
        #pragma unroll
        for (int j=0;j<8;++j){
          float4 h4 = *(const float4*)(&s_he[tr*8+j][dd]);
          acc[j][0] = fmaf(h4.x,w0.x,fmaf(h4.y,w1.x,fmaf(h4.z,w2.x,fmaf(h4.w,w3.x,acc[j][0]))));
          acc[j][1] = fmaf(h4.x,w0.y,fmaf(h4.y,w1.y,fmaf(h4.z,w2.y,fmaf(h4.w,w3.y,acc[j][1]))));
          acc[j][2] = fmaf(h4.x,w0.z,fmaf(h4.y,w1.z,fmaf(h4.z,w2.z,fmaf(h4.w,w3.z,acc[j][2]))));
          acc[j][3] = fmaf(h4.x,w0.w,fmaf(h4.y,w1.w,fmaf(h4.z,w2.w,fmaf(h4.w,w3.w,acc[j][3]))));
        }
      }
      #pragma unroll
      for (int j=0;j<8;++j){
        int tt = tr*8+j;
        s_u[tt][4*c4+0] = siluf(acc[j][0]);
        s_u[tt][4*c4+1] = siluf(acc[j][1]);
        s_u[tt][4*c4+2] = siluf(acc[j][2]);
        s_u[tt][4*c4+3] = siluf(acc[j][3]);
      }
    }
  }
  __syncthreads();
  // W_pg2: 8 tok x 2 STRIDED cols per thread (c2, c2+128) -> coalesced atomics
  {
    int c2 = tid & 127;
    int tr = tid >> 7;
    float acc[8][2];
    #pragma unroll
    for (int j=0;j<8;++j){ acc[j][0]=0.f; acc[j][1]=0.f; }
    const float* Wp2 = W_pg2 + (size_t)g*80896 + c2;
    for (int p=0; p<DPG_; p+=4){
      float w[4][2];
      #pragma unroll
      for (int r=0;r<4;++r){
        const float* Wr = Wp2 + (size_t)(p+r)*256;
        w[r][0] = Wr[0]; w[r][1] = Wr[128];
      }
      #pragma unroll
      for (int j=0;j<8;++j){
        float4 u4 = *(const float4*)(&s_u[tr*8+j][p]);
        acc[j][0] = fmaf(u4.x,w[0][0],fmaf(u4.y,w[1][0],fmaf(u4.z,w[2][0],fmaf(u4.w,w[3][0],acc[j][0]))));
        acc[j][1] = fmaf(u4.x,w[0][1],fmaf(u4.y,w[1][1],fmaf(u4.z,w[2][1],fmaf(u4.w,w[3][1],acc[j][1]))));
      }
    }
    #pragma unroll
    for (int j=0;j<8;++j){
      int tt = tr*8+j;
      if (tt < nact){
        float* dst = ws + OFF_ACCPOST + (size_t)s_tok[tt]*256 + c2;
        unsafeAtomicAdd(dst+0,   sigf(acc[j][0]));
        unsafeAtomicAdd(dst+128, sigf(acc[j][1]));
      }
    }
  }
}

// ---------------- K4: KDA delta-rule recurrence ----------------
__global__ __launch_bounds__(256) void k_kda(float* ws){
  int hb = blockIdx.x; int h = hb>>2, b = hb&3;
  int tid = threadIdx.x;
  int e = tid >> 2, dg = tid & 3;
  const float* qb = ws + OFF_QH  + ((size_t)h*BT_ + b*T_)*32;
  const float* kb = ws + OFF_KH  + ((size_t)h*BT_ + b*T_)*32;
  const float* ab = ws + OFF_ALH + ((size_t)h*BT_ + b*T_)*32;
  const float* vb = ws + OFF_VH  + ((size_t)h*BT_ + b*T_)*64;
  const float* bb = ws + OFF_BEH + (size_t)h*BT_ + b*T_;
  float* ob = ws + OFF_ATTN + (size_t)b*T_*512 + h*64;

  __shared__ float s_q[TT*32];
  __shared__ float s_k[TT*32];
  __shared__ float s_a[TT*32];
  __shared__ float s_v[TT*64];
  __shared__ float s_b[TT];
  __shared__ float s_o[TT*64];

  float S[8];
  #pragma unroll
  for (int j=0;j<8;++j) S[j]=0.f;

  for (int t0=0; t0<T_; t0+=TT){
    {
      const float4* q4 = (const float4*)(qb + t0*32);
      const float4* k4 = (const float4*)(kb + t0*32);
      const float4* a4 = (const float4*)(ab + t0*32);
      const float4* v4 = (const float4*)(vb + t0*64);
      #pragma unroll
      for (int r=0;r<2;++r){
        int i = r*256 + tid;
        ((float4*)s_q)[i] = q4[i];
        ((float4*)s_k)[i] = k4[i];
        ((float4*)s_a)[i] = a4[i];
      }
      #pragma unroll
      for (int r=0;r<4;++r){
        int i = r*256 + tid;
        ((float4*)s_v)[i] = v4[i];
      }
      if (tid < TT) s_b[tid] = bb[t0+tid];
    }
    __syncthreads();
    #pragma unroll 4
    for (int tt=0; tt<TT; ++tt){
      const float* kp = s_k + tt*32 + dg*8;
      const float* ap = s_a + tt*32 + dg*8;
      const float* qp = s_q + tt*32 + dg*8;
      float v  = s_v[tt*64 + e];
      float be = s_b[tt];
      float part = 0.f;
      float kv[8], av[8];
      #pragma unroll
      for (int j=0;j<8;++j){ kv[j]=kp[j]; av[j]=ap[j]; part = fmaf(kv[j]*av[j], S[j], part); }
      part += __shfl_xor(part, 1, 4);
      part += __shfl_xor(part, 2, 4);
      float w = be*(v - part);
      float op = 0.f;
      #pragma unroll
      for (int j=0;j<8;++j){
        S[j] = fmaf(w, kv[j], av[j]*S[j]);
        op = fmaf(qp[j], S[j], op);
      }
      op += __shfl_xor(op, 1, 4);
      op += __shfl_xor(op, 2, 4);
      if (dg==0) s_o[tt*64 + e] = op / 22.627416997969522f;
    }
    __syncthreads();
    for (int i=tid; i<TT*16; i+=256){
      int tt = i>>4, c = i&15;
      ((float4*)(ob + (size_t)(t0+tt)*512))[c] = ((const float4*)(s_o + tt*64))[c];
    }
  }
}

// ---------------- K5: W_o epilogue + stream mixing ----------------
__global__ __launch_bounds__(256) void k_final(const float* __restrict__ stream,
    const float* __restrict__ W_o, float* ws, float* __restrict__ out){
  __shared__ float s_m[8][512];
  __shared__ float s_rs[8][16];
  __shared__ float s_hp[8][4];
  int tid = threadIdx.x;
  int t0 = blockIdx.x*8;
  for (int tt=0;tt<8;++tt){
    int tok = t0+tt;
    for (int idx=tid; idx<512; idx+=256)
      s_m[tt][idx] = ws[OFF_ATTN + (size_t)tok*512 + idx] * (0.125f*ws[OFF_ACCPRE + (size_t)tok*512 + idx]);
    if (tid<16) s_rs[tt][tid] = 0.125f*ws[OFF_ACCRES + tok*16 + tid];
    if (tid<4)  s_hp[tt][tid] = 0.125f*ws[OFF_ACCHP + tok*4 + tid];
  }
  __syncthreads();
  float facc[8];
  #pragma unroll
  for (int tt=0;tt<8;++tt) facc[tt]=0.f;
  const float* Wop = W_o + tid;
  for (int cc=0;cc<512;++cc){
    float w = Wop[(size_t)cc*256];
    #pragma unroll
    for (int tt=0;tt<8;++tt) facc[tt] = fmaf(s_m[tt][cc], w, facc[tt]);
  }
  for (int tt=0;tt<8;++tt){
    int tok=t0+tt; int b=tok>>10, t=tok&1023;
    float result = facc[tt]*(0.125f*ws[OFF_ACCPOST + (size_t)tok*256 + tid]);
    float st[4];
    #pragma unroll
    for (int j=0;j<4;++j) st[j]=stream[(((size_t)b*4+j)*1024+t)*256+tid];
    #pragma unroll
    for (int n=0;n<4;++n){
      float rv = fmaf(s_rs[tt][n*4+3], st[3],
                 fmaf(s_rs[tt][n*4+2], st[2],
                 fmaf(s_rs[tt][n*4+1], st[1], s_rs[tt][n*4]*st[0])));
      out[(((size_t)b*4+n)*1024+t)*256+tid] = rv + s_hp[tt][n]*result;
    }
  }
}

extern "C" void kernel_launch(void* const* d_in, const int* in_sizes, int n_in,
                              void* d_out, int out_size, void* d_ws, size_t ws_size,
                              hipStream_t stream){
  const float* s = (const float*)d_in[0];
  float* ws = (float*)d_ws;
  hipMemsetAsync(d_ws, 0, (size_t)ZERO_END*4, stream);
  k_trig<<<64,256,0,stream>>>((const float*)d_in[4], ws);
  k_route<<<4096,256,0,stream>>>(s, (const float*)d_in[5], (const float*)d_in[6], ws);
  dim3 gh(BT_/TBH, 32);
  k_he_kv<<<gh,256,0,stream>>>(s, ws,
      (const float*)d_in[17], (const float*)d_in[18],
      (const float*)d_in[19], (const float*)d_in[20],
      (const float*)d_in[21], (const float*)d_in[22], (const float*)d_in[23],
      (const float*)d_in[24], (const float*)d_in[25], (const float*)d_in[26],
      (const float*)d_in[27]);
  k_he_q<<<gh,256,0,stream>>>(s, ws,
      (const float*)d_in[17], (const float*)d_in[18],
      (const float*)d_in[21], (const float*)d_in[24],
      (const float*)d_in[27]);
  dim3 gp(BT_/TB, 32);
  k_proj_kv<<<gp,512,0,stream>>>(ws,
      (const float*)d_in[2],  (const float*)d_in[3],
      (const float*)d_in[9],  (const float*)d_in[10],
      (const float*)d_in[11], (const float*)d_in[12],
      (const float*)d_in[13], (const float*)d_in[14],
      (const float*)d_in[15], (const float*)d_in[16],
      (const float*)d_in[28]);
  k_proj_q<<<gp,512,0,stream>>>(ws,
      (const float*)d_in[1],  (const float*)d_in[7], (const float*)d_in[8],
      (const float*)d_in[30], (const float*)d_in[31]);
  k_kda<<<32,256,0,stream>>>(ws);
  k_final<<<512,256,0,stream>>>(s, (const float*)d_in[29], ws, (float*)d_out);
}